// Round 15
// baseline (1419.756 us; speedup 1.0000x reference)
//
#include <hip/hip_runtime.h>
#include <hip/hip_bf16.h>
#include <math.h>

#define NTOK 8192     // B*S
#define DMD  2048     // d_model
#define DCC  512      // d_cortical
#define TOKH 4194304  // NTOK*DCC

typedef __attribute__((ext_vector_type(8))) short short8;
typedef __attribute__((ext_vector_type(4))) float f32x4;

// ---------------- helpers ---------------------------------------------------
__device__ inline float bf2f(unsigned short u) {
    union { unsigned int i; float f; } x; x.i = ((unsigned int)u) << 16; return x.f;
}
__device__ inline unsigned short f2bf(float f) {
    union { float f; unsigned int i; } x; x.f = f;
    unsigned int u = x.i;
    return (unsigned short)((u + 0x7fffu + ((u >> 16) & 1u)) >> 16);
}

typedef const __attribute__((address_space(1))) unsigned int* gas1_t;
typedef __attribute__((address_space(3))) unsigned int* las3_t;
__device__ inline void async16(const void* g, void* l) {
    __builtin_amdgcn_global_load_lds(
        (gas1_t)g,
        (las3_t)(unsigned int)(unsigned long long)l, 16, 0, 0);
}

#define VMCNT(N) asm volatile("s_waitcnt vmcnt(" #N ")" ::: "memory")

// ---------------- fp32 -> bf16 bulk conversion (grid-stride) ----------------
__global__ __launch_bounds__(256)
void cvt_kernel(const float* __restrict__ s, unsigned short* __restrict__ d, int n4)
{
    for (int i = blockIdx.x * 256 + threadIdx.x; i < n4; i += gridDim.x * 256) {
        float4 v = ((const float4*)s)[i];
        ushort4 o;
        o.x = f2bf(v.x); o.y = f2bf(v.y); o.z = f2bf(v.z); o.w = f2bf(v.w);
        ((ushort4*)d)[i] = o;
    }
}

// ---------------- merged fp32 -> bf16 weight conversion ---------------------
struct CvtArgs { const float* src[6]; };

__global__ __launch_bounds__(256)
void wcvt_kernel(CvtArgs ca, unsigned short* __restrict__ dst)
{
    const int total = 1310720;  // f4 units
    for (int i = blockIdx.x * 256 + threadIdx.x; i < total; i += gridDim.x * 256) {
        const float* sp; int base;
        if      (i <  262144) { sp = ca.src[0]; base = 0;       }  // fuse_W
        else if (i <  524288) { sp = ca.src[1]; base = 262144;  }  // up_W
        else if (i <  786432) { sp = ca.src[2]; base = 524288;  }  // lateral_W
        else if (i <  983040) { sp = ca.src[3]; base = 786432;  }  // down_W
        else if (i < 1048576) { sp = ca.src[4]; base = 983040;  }  // out1_W
        else                  { sp = ca.src[5]; base = 1048576; }  // out2_W
        float4 v = ((const float4*)sp)[i - base];
        ushort4 o;
        o.x = f2bf(v.x); o.y = f2bf(v.y); o.z = f2bf(v.z); o.w = f2bf(v.w);
        ((ushort4*)dst)[i] = o;
    }
}

// ---------------- proj_W transpose: (4,512,2048) f32 -> (4,2048,512) bf16 ---
__global__ __launch_bounds__(256)
void ptr_kernel(const float* __restrict__ src, unsigned short* __restrict__ dst)
{
    __shared__ float t[32][33];
    const int o  = blockIdx.z;
    const int jb = blockIdx.x * 32;
    const int kb = blockIdx.y * 32;
    const int r  = threadIdx.x >> 3;
    const int c4 = (threadIdx.x & 7) * 4;
    {
        const float* s = src + ((size_t)o * DCC + kb + r) * DMD + jb + c4;
        float4 v = *(const float4*)s;
        t[r][c4+0]=v.x; t[r][c4+1]=v.y; t[r][c4+2]=v.z; t[r][c4+3]=v.w;
    }
    __syncthreads();
    {
        ushort4 u;
        u.x = f2bf(t[c4+0][r]); u.y = f2bf(t[c4+1][r]);
        u.z = f2bf(t[c4+2][r]); u.w = f2bf(t[c4+3][r]);
        *(ushort4*)(dst + ((size_t)o * DMD + jb + r) * DCC + kb + c4) = u;
    }
}

// ---------------- b' = fuse_b + fuse_W @ proj_b_flat (exact f32) ------------
__global__ __launch_bounds__(256)
void bprime_kernel(const float* __restrict__ fuse_W, const float* __restrict__ fuse_b,
                   const float* __restrict__ proj_b, float* __restrict__ bp)
{
    const int row = blockIdx.x * 8 + (threadIdx.x >> 5);
    const int l32 = threadIdx.x & 31;
    const float* r = fuse_W + (size_t)row * (4 * DCC) + l32 * 64;
    const float* p = proj_b + l32 * 64;
    float s = 0.f;
    #pragma unroll
    for (int k = 0; k < 64; k += 4) {
        float4 v = *(const float4*)(r + k);
        float4 q = *(const float4*)(p + k);
        s += v.x*q.x + v.y*q.y + v.z*q.z + v.w*q.w;
    }
    #pragma unroll
    for (int off = 16; off; off >>= 1) s += __shfl_xor(s, off, 64);
    if (l32 == 0) bp[row] = s + fuse_b[row];
}

// ---------------- batched bf16 MFMA GEMM (counted-vmcnt pipeline) -----------
struct GArgs {
    const unsigned short* A[6];
    const unsigned short* W[6];
    const float*          bias[6];
    const float*          add[6];
    void*                 C[6];
};

template<bool OUTF32, bool GELU>
__global__ __launch_bounds__(256)
void gemm16(GArgs ga, int lda, int ldw, int ldadd, int ldc, int K)
{
    __shared__ unsigned short As[3][128 * 32];   // 24 KB
    __shared__ unsigned short Bs[3][128 * 32];   // 24 KB

    const int z    = blockIdx.z;
    const int tid  = threadIdx.x;
    const int wave = tid >> 6;
    const int lane = tid & 63;

    const int nwg   = gridDim.x * gridDim.y;
    const int bid   = blockIdx.y * gridDim.x + blockIdx.x;
    const int swz   = (bid & 7) * (nwg >> 3) + (bid >> 3);
    const int bn    = (swz % gridDim.x) * 128;
    const int bm    = (swz / gridDim.x) * 128;

    const int wr   = wave >> 1;
    const int wc   = wave & 1;

    const unsigned short* Ap = ga.A[z];
    const unsigned short* Wp = ga.W[z];

    const int lrow = lane >> 2;
    const int lcol = (lane & 3) * 8;
    const int l15  = lane & 15;
    const int lh   = lane >> 4;

    f32x4 acc[4][4] = {};

    const int nsteps = K >> 5;

    auto issue = [&](int buf, int k0) {
        #pragma unroll
        for (int r = 0; r < 2; ++r) {
            int c = wave + r * 4;
            async16(Ap + (size_t)(bm + c * 16 + lrow) * lda + k0 + lcol,
                    &As[buf][c * 512]);
            async16(Wp + (size_t)(bn + c * 16 + lrow) * ldw + k0 + lcol,
                    &Bs[buf][c * 512]);
        }
    };

    issue(0, 0);
    issue(1, 32);

    for (int t = 0; t < nsteps; ++t) {
        const int cur = t % 3;
        if (t + 2 < nsteps) issue((t + 2) % 3, (t + 2) * 32);
        const int rem = nsteps - 1 - t;
        if (rem >= 2)      VMCNT(8);
        else if (rem == 1) VMCNT(4);
        else               VMCNT(0);
        __builtin_amdgcn_s_barrier();     // publish buf[cur]

        short8 af[4], bfr[4];
        #pragma unroll
        for (int i = 0; i < 4; ++i) {
            af[i]  = *(const short8*)&As[cur][(wr * 64 + i * 16 + l15) * 32 + lh * 8];
            bfr[i] = *(const short8*)&Bs[cur][(wc * 64 + i * 16 + l15) * 32 + lh * 8];
        }
        __builtin_amdgcn_s_setprio(1);
        #pragma unroll
        for (int mi = 0; mi < 4; ++mi)
            #pragma unroll
            for (int ni = 0; ni < 4; ++ni)
                acc[mi][ni] = __builtin_amdgcn_mfma_f32_16x16x32_bf16(
                    af[mi], bfr[ni], acc[mi][ni], 0, 0, 0);
        __builtin_amdgcn_s_setprio(0);
        __builtin_amdgcn_s_barrier();     // buf[cur] reads done
    }

    const float* bias = ga.bias[z];
    const float* add  = ga.add[z];
    #pragma unroll
    for (int ni = 0; ni < 4; ++ni) {
        int col = bn + wc * 64 + ni * 16 + l15;
        float bv = bias ? bias[col] : 0.0f;
        #pragma unroll
        for (int mi = 0; mi < 4; ++mi) {
            #pragma unroll
            for (int r = 0; r < 4; ++r) {
                int row = bm + wr * 64 + mi * 16 + lh * 4 + r;
                float vv = acc[mi][ni][r] + bv;
                if (GELU) vv = 0.5f * vv * (1.0f + erff(vv * 0.7071067811865475f));
                if (OUTF32) {
                    if (add) vv += add[(size_t)row * ldadd + col];
                    ((float*)ga.C[z])[(size_t)row * ldc + col] = vv;
                } else {
                    ((unsigned short*)ga.C[z])[(size_t)row * ldc + col] = f2bf(vv);
                }
            }
        }
    }
}

// ---------------- x0 reduce: x0 = bf16(sum_o partial_o + b') ----------------
__global__ __launch_bounds__(256)
void x0red(const float* __restrict__ partial, const float* __restrict__ bp,
           unsigned short* __restrict__ x0)
{
    const int i = blockIdx.x * 256 + threadIdx.x;   // f4 units, total 1048576
    float4 a = ((const float4*)partial)[i];
    float4 b = ((const float4*)(partial + TOKH))[i];
    float4 c = ((const float4*)(partial + 2 * (size_t)TOKH))[i];
    float4 d = ((const float4*)(partial + 3 * (size_t)TOKH))[i];
    const int col = (i * 4) & (DCC - 1);
    float4 bv = *(const float4*)(bp + col);
    ushort4 o;
    o.x = f2bf(a.x + b.x + c.x + d.x + bv.x);
    o.y = f2bf(a.y + b.y + c.y + d.y + bv.y);
    o.z = f2bf(a.z + b.z + c.z + d.z + bv.z);
    o.w = f2bf(a.w + b.w + c.w + d.w + bv.w);
    ((ushort4*)x0)[i] = o;
}

// ---------------- fused GEMM + LN (+update), 4-deep counted-vmcnt -----------
// 32 rows x 512 cols, K=512, 512 threads / 8 waves, grid 256 (1 block/CU,
// grid-limited -> extra LDS free). 4-deep buffers, loads 3 steps ahead; own-
// batch wait = 3 younger batches: vmcnt 15/12 steady, 10/8 -> 5/4 -> 0 tail.
// LDS: Bs 4x32K + As4 4x2K + red 2K = 138 KB.
__device__ inline int csw(int rl, int col) {
    int s = ((rl >> 2) & 3) ^ (rl & 3);
    return rl * 512 + (col ^ (s << 4));
}

template<int MODE>
__global__ __launch_bounds__(512)
void gemm_fused(const unsigned short* __restrict__ Ap,
                const unsigned short* __restrict__ Wp,
                const float* __restrict__ bias,
                const float* __restrict__ g,
                const float* __restrict__ b,
                const unsigned short* a_in,
                const unsigned short* t_in,
                const unsigned short* __restrict__ lat_in,
                const float* __restrict__ logit,
                unsigned short* outp)
{
    __shared__ unsigned short Bs[4][512 * 32];   // 128 KB
    __shared__ unsigned short As4[4][32 * 32];   //   8 KB
    __shared__ float red[2][8][32];              //   2 KB

    const int tid  = threadIdx.x;
    const int wave = tid >> 6;         // 0..7
    const int lane = tid & 63;
    const int lrow = lane >> 2;        // 0..15
    const int lc8  = (lane & 3) * 8;   // 0,8,16,24
    const int bm   = blockIdx.x * 32;
    const int l15  = lane & 15;
    const int lh   = lane >> 4;
    const int c0   = lane * 8;

    f32x4 acc[2][4] = {};

    auto issue = [&](int buf, int k0) {
        if (wave < 2)
            async16(Ap + (size_t)(bm + wave * 16 + lrow) * DCC + k0 + lc8,
                    &As4[buf][wave * 512]);
        #pragma unroll
        for (int r = 0; r < 4; ++r)
            async16(Wp + (size_t)((r * 8 + wave) * 16 + lrow) * DCC + k0 + lc8,
                    &Bs[buf][(r * 8 + wave) * 512]);
    };

    issue(0, 0);
    issue(1, 32);
    issue(2, 64);

    #pragma unroll
    for (int t = 0; t < 16; ++t) {
        const int cur = t & 3;
        if (t + 3 < 16) issue((t + 3) & 3, (t + 3) * 32);
        const int rem = 15 - t;   // younger batches in flight
        if (rem >= 3)      { if (wave < 2) VMCNT(15); else VMCNT(12); }
        else if (rem == 2) { if (wave < 2) VMCNT(10); else VMCNT(8); }
        else if (rem == 1) { if (wave < 2) VMCNT(5);  else VMCNT(4); }
        else               { VMCNT(0); }
        __builtin_amdgcn_s_barrier();   // publish buf[cur]
        short8 af[2], bfr[4];
        #pragma unroll
        for (int mi = 0; mi < 2; ++mi)
            af[mi] = *(const short8*)&As4[cur][(mi * 16 + l15) * 32 + lh * 8];
        #pragma unroll
        for (int ni = 0; ni < 4; ++ni)
            bfr[ni] = *(const short8*)&Bs[cur][(wave * 64 + ni * 16 + l15) * 32 + lh * 8];
        __builtin_amdgcn_s_setprio(1);
        #pragma unroll
        for (int mi = 0; mi < 2; ++mi)
            #pragma unroll
            for (int ni = 0; ni < 4; ++ni)
                acc[mi][ni] = __builtin_amdgcn_mfma_f32_16x16x32_bf16(
                    af[mi], bfr[ni], acc[mi][ni], 0, 0, 0);
        __builtin_amdgcn_s_setprio(0);
        __builtin_amdgcn_s_barrier();   // reads of buf[cur] done
    }

    // ---- LN1 row stats in MFMA layout ----
    float bv[4], gv[4], bbv[4];
    #pragma unroll
    for (int ni = 0; ni < 4; ++ni) {
        int col = wave * 64 + ni * 16 + l15;
        bv[ni] = bias[col]; gv[ni] = g[col]; bbv[ni] = b[col];
    }

    float ps[2][4], pq[2][4];
    #pragma unroll
    for (int mi = 0; mi < 2; ++mi)
        #pragma unroll
        for (int rr = 0; rr < 4; ++rr) {
            float s = 0.f, q = 0.f;
            #pragma unroll
            for (int ni = 0; ni < 4; ++ni) {
                float v = acc[mi][ni][rr] + bv[ni];
                acc[mi][ni][rr] = v;
                s += v; q += v * v;
            }
            #pragma unroll
            for (int off = 1; off < 16; off <<= 1) {
                s += __shfl_xor(s, off, 64);
                q += __shfl_xor(q, off, 64);
            }
            ps[mi][rr] = s; pq[mi][rr] = q;
        }
    if (l15 == 0) {
        #pragma unroll
        for (int mi = 0; mi < 2; ++mi)
            #pragma unroll
            for (int rr = 0; rr < 4; ++rr) {
                int rl = mi * 16 + lh * 4 + rr;
                red[0][wave][rl] = ps[mi][rr];
                red[1][wave][rl] = pq[mi][rr];
            }
    }
    __syncthreads();

    // comp = LN1 result -> compS (reuse Bs[0]; K-loop fully done)
    unsigned short* compS = &Bs[0][0];
    #pragma unroll
    for (int mi = 0; mi < 2; ++mi)
        #pragma unroll
        for (int rr = 0; rr < 4; ++rr) {
            int rl = mi * 16 + lh * 4 + rr;
            float s = 0.f, q = 0.f;
            #pragma unroll
            for (int w = 0; w < 8; ++w) { s += red[0][w][rl]; q += red[1][w][rl]; }
            float m1 = s * (1.0f / DCC);
            float r1 = rsqrtf(q * (1.0f / DCC) - m1 * m1 + 1e-5f);
            #pragma unroll
            for (int ni = 0; ni < 4; ++ni) {
                int col = wave * 64 + ni * 16 + l15;
                compS[csw(rl, col)] = f2bf((acc[mi][ni][rr] - m1) * r1 * gv[ni] + bbv[ni]);
            }
        }
    __syncthreads();

    // ---- phase 2: row-mapped (wave owns 4 rows, lane owns 8 contiguous cols)
    if constexpr (MODE == 0) {
        #pragma unroll
        for (int rr = 0; rr < 4; ++rr) {
            const int rl = wave * 4 + rr;
            const size_t gbase = (size_t)(bm + rl) * DCC + c0;
            short8 cm = *(const short8*)&compS[csw(rl, c0)];
            *(short8*)(outp + gbase) = cm;
        }
    } else {
        float gr[8], br[8], pr[8];
        {
            float4 g0 = *(const float4*)(g + c0),     g1 = *(const float4*)(g + c0 + 4);
            float4 b0 = *(const float4*)(b + c0),     b1 = *(const float4*)(b + c0 + 4);
            float4 p0 = *(const float4*)(logit + c0), p1 = *(const float4*)(logit + c0 + 4);
            float gt[8] = {g0.x,g0.y,g0.z,g0.w,g1.x,g1.y,g1.z,g1.w};
            float bt[8] = {b0.x,b0.y,b0.z,b0.w,b1.x,b1.y,b1.z,b1.w};
            float pt[8] = {p0.x,p0.y,p0.z,p0.w,p1.x,p1.y,p1.z,p1.w};
            #pragma unroll
            for (int j = 0; j < 8; ++j) {
                gr[j] = gt[j]; br[j] = bt[j];
                pr[j] = 1.0f / (1.0f + __expf(-pt[j]));
            }
        }
        #pragma unroll
        for (int rr = 0; rr < 4; ++rr) {
            const int rl = wave * 4 + rr;
            const size_t gbase = (size_t)(bm + rl) * DCC + c0;
            short8 cm = *(const short8*)&compS[csw(rl, c0)];
            short8 ar = *(const short8*)(a_in + gbase);
            short8 tr = *(const short8*)(t_in + gbase);
            short8 lr = *(const short8*)(lat_in + gbase);
            float tv[8], s = 0.f, q = 0.f;
            #pragma unroll
            for (int j = 0; j < 8; ++j) {
                float val = bf2f((unsigned short)ar[j])
                          + 0.5f * (bf2f((unsigned short)cm[j]) - bf2f((unsigned short)tr[j])) * pr[j]
                          + 0.1f * bf2f((unsigned short)lr[j]);
                tv[j] = val; s += val; q += val * val;
            }
            #pragma unroll
            for (int off = 1; off < 64; off <<= 1) {
                s += __shfl_xor(s, off, 64);
                q += __shfl_xor(q, off, 64);
            }
            float m2 = s * (1.0f / DCC);
            float r2 = rsqrtf(q * (1.0f / DCC) - m2 * m2 + 1e-5f);
            short8 o;
            #pragma unroll
            for (int j = 0; j < 8; ++j)
                o[j] = (short)f2bf((tv[j] - m2) * r2 * gr[j] + br[j]);
            *(short8*)(outp + gbase) = o;
        }
    }
}

// ---------------------------------------------------------------------------
extern "C" void kernel_launch(void* const* d_in, const int* in_sizes, int n_in,
                              void* d_out, int out_size, void* d_ws, size_t ws_size,
                              hipStream_t stream)
{
    const float* qwen   = (const float*)d_in[0];
    const float* obs    = (const float*)d_in[1];
    const float* proj_W = (const float*)d_in[2];
    const float* proj_b = (const float*)d_in[3];
    const float* fuse_W = (const float*)d_in[4];
    const float* fuse_b = (const float*)d_in[5];
    const float* up_W   = (const float*)d_in[6];
    const float* up_b   = (const float*)d_in[7];
    const float* lat_W  = (const float*)d_in[8];
    const float* lat_b  = (const float*)d_in[9];
    const float* plogit = (const float*)d_in[10];
    const float* ln_g   = (const float*)d_in[11];
    const float* ln_b   = (const float*)d_in[12];
    const float* down_W = (const float*)d_in[13];
    const float* down_b = (const float*)d_in[14];
    const float* out1_W = (const float*)d_in[15];
    const float* out1_b = (const float*)d_in[16];
    const float* out2_W = (const float*)d_in[17];
    const float* out2_b = (const float*)d_in[18];
    float* out = (float*)d_out;

    // ---- ws layout (ushort); footprint 228.6 MB (proven)
    unsigned short* wsu = (unsigned short*)d_ws;
    float*          bp     = (float*)wsu;                  // 512 f32
    unsigned short* h16    = wsu + 2048;                   // head scratch
    unsigned short* M16    = wsu + 8388608;                // (4,512,2048)
    unsigned short* x0b    = wsu + 16777216;
    unsigned short* acts16[4] = {
        wsu + 20971520, wsu + 20971520 + TOKH,
        wsu + 20971520 + 2 * TOKH, wsu + 20971520 + 3 * TOKH };
    unsigned short* w16    = wsu + 37748736;
    unsigned short* fuseW16 = w16;
    unsigned short* upW16   = w16 + 1048576;
    unsigned short* latW16  = w16 + 2097152;
    unsigned short* downW16 = w16 + 3145728;
    unsigned short* out1W16 = w16 + 3932160;
    unsigned short* out2W16 = w16 + 4194304;
    unsigned short* projT16 = wsu + 47185920;              // (4,2048,512)
    unsigned short* obs16   = wsu + 47185920;              // overlays projT16

    // d_out overlays: part32 (front); pred a/b + lat0..3 (settle)
    float*          part32  = (float*)d_out;
    unsigned short* outu = (unsigned short*)d_out;
    unsigned short* pred16a = outu;
    unsigned short* pred16b = outu + TOKH;
    unsigned short* lat16[4] = { outu + 2*TOKH, outu + 3*TOKH, outu + 4*TOKH, outu + 5*TOKH };

    dim3 blk(256);
    dim3 blk512(512);

    {
        CvtArgs ca;
        ca.src[0] = fuse_W; ca.src[1] = up_W;   ca.src[2] = lat_W;
        ca.src[3] = down_W; ca.src[4] = out1_W; ca.src[5] = out2_W;
        wcvt_kernel<<<dim3(2048), blk, 0, stream>>>(ca, w16);
    }
    ptr_kernel<<<dim3(DMD/32, DCC/32, 4), blk, 0, stream>>>(proj_W, projT16);
    bprime_kernel<<<dim3(DCC/8), blk, 0, stream>>>(fuse_W, fuse_b, proj_b, bp);

    // ---- M_o = fuseW_o @ projW_o  (512x2048 each, K=512); consumes projT16
    {
        GArgs a{};
        for (int o = 0; o < 4; ++o) {
            a.A[o] = fuseW16 + o * DCC;
            a.W[o] = projT16 + (size_t)o * DMD * DCC;
            a.bias[o] = nullptr;
            a.C[o] = M16 + (size_t)o * DCC * DMD;
        }
        gemm16<false, false><<<dim3(DMD/128, DCC/128, 4), blk, 0, stream>>>(
            a, 4 * DCC, DCC, 0, DMD, DCC);
    }

    // ---- obs -> bf16 (one BW-bound pass; overwrites dead projT16 region)
    cvt_kernel<<<dim3(4096), blk, 0, stream>>>(obs, obs16, 16777216);

    // ---- x0 split-K partials: pure-bf16 gemm16, grid 1024 = ~3-4 blocks/CU
    {
        GArgs a{};
        for (int o = 0; o < 4; ++o) {
            a.A[o] = obs16 + (size_t)o * NTOK * DMD;
            a.W[o] = M16 + (size_t)o * DCC * DMD;
            a.bias[o] = nullptr;
            a.add[o]  = nullptr;
            a.C[o] = part32 + (size_t)o * TOKH;
        }
        gemm16<true, false><<<dim3(DCC/128, NTOK/128, 4), blk, 0, stream>>>(
            a, DMD, DMD, 0, DCC, DMD);
    }
    // ---- x0 = bf16(sum partials + b')
    x0red<<<dim3(TOKH/4/256), blk, 0, stream>>>(part32, bp, x0b);

    dim3 fgrid(NTOK / 32);   // 256 blocks = 1 block/CU

    // ---- initial bottom-up pass
    for (int i = 0; i < 4; ++i) {
        gemm_fused<0><<<fgrid, blk512, 0, stream>>>(
            (i == 0) ? x0b : acts16[i - 1],
            upW16 + (size_t)i * DCC * DCC, up_b + i * DCC,
            ln_g + i * DCC, ln_b + i * DCC,
            nullptr, nullptr, nullptr, nullptr, acts16[i]);
    }

    // ---- settling iterations
    for (int s = 0; s < 5; ++s) {
        {
            GArgs a{};
            a.A[0] = acts16[1]; a.W[0] = downW16 + (size_t)1 * DCC * DCC;
            a.bias[0] = down_b + 1 * DCC; a.C[0] = pred16a;
            a.A[1] = acts16[2]; a.W[1] = downW16 + (size_t)2 * DCC * DCC;
            a.bias[1] = down_b + 2 * DCC; a.C[1] = pred16b;
            for (int i = 0; i < 4; ++i) {
                a.A[2 + i] = acts16[i];
                a.W[2 + i] = latW16 + (size_t)i * DCC * DCC;
                a.bias[2 + i] = lat_b + i * DCC;
                a.C[2 + i] = lat16[i];
            }
            gemm16<false, false><<<dim3(DCC/128, NTOK/128, 6), blk, 0, stream>>>(
                a, DCC, DCC, 0, DCC, DCC);
        }
        for (int i = 0; i < 4; ++i) {
            const unsigned short* tgt =
                (i == 0) ? pred16a : (i == 1) ? pred16b : acts16[i];
            gemm_fused<1><<<fgrid, blk512, 0, stream>>>(
                (i == 0) ? x0b : acts16[i - 1],
                upW16 + (size_t)i * DCC * DCC, up_b + i * DCC,
                ln_g + i * DCC, ln_b + i * DCC,
                acts16[i], tgt, lat16[i], plogit + i * DCC, acts16[i]);
        }
    }

    // ---- head
    {
        GArgs a{};
        a.A[0] = acts16[3]; a.W[0] = out1W16; a.bias[0] = out1_b; a.C[0] = h16;
        gemm16<false, true><<<dim3(DCC/128, NTOK/128, 1), blk, 0, stream>>>(
            a, DCC, DCC, 0, DCC, DCC);
    }
    {
        GArgs a{};
        a.A[0] = h16; a.W[0] = out2W16; a.bias[0] = out2_b;
        a.add[0] = qwen; a.C[0] = out;
        gemm16<true, false><<<dim3(DMD/128, NTOK/128, 1), blk, 0, stream>>>(
            a, DCC, DCC, DMD, DMD, DCC);
    }
}

// Round 16
// 1412.659 us; speedup vs baseline: 1.0050x; 1.0050x over previous
//
#include <hip/hip_runtime.h>
#include <hip/hip_bf16.h>
#include <math.h>

#define NTOK 8192     // B*S
#define DMD  2048     // d_model
#define DCC  512      // d_cortical
#define TOKH 4194304  // NTOK*DCC

typedef __attribute__((ext_vector_type(8))) short short8;
typedef __attribute__((ext_vector_type(4))) float f32x4;

// ---------------- helpers ---------------------------------------------------
__device__ inline float bf2f(unsigned short u) {
    union { unsigned int i; float f; } x; x.i = ((unsigned int)u) << 16; return x.f;
}
__device__ inline unsigned short f2bf(float f) {
    union { float f; unsigned int i; } x; x.f = f;
    unsigned int u = x.i;
    return (unsigned short)((u + 0x7fffu + ((u >> 16) & 1u)) >> 16);
}

typedef const __attribute__((address_space(1))) unsigned int* gas1_t;
typedef __attribute__((address_space(3))) unsigned int* las3_t;
__device__ inline void async16(const void* g, void* l) {
    __builtin_amdgcn_global_load_lds(
        (gas1_t)g,
        (las3_t)(unsigned int)(unsigned long long)l, 16, 0, 0);
}

#define VMCNT(N) asm volatile("s_waitcnt vmcnt(" #N ")" ::: "memory")

// ---------------- fp32 -> bf16 bulk conversion (grid-stride) ----------------
__global__ __launch_bounds__(256)
void cvt_kernel(const float* __restrict__ s, unsigned short* __restrict__ d, int n4)
{
    for (int i = blockIdx.x * 256 + threadIdx.x; i < n4; i += gridDim.x * 256) {
        float4 v = ((const float4*)s)[i];
        ushort4 o;
        o.x = f2bf(v.x); o.y = f2bf(v.y); o.z = f2bf(v.z); o.w = f2bf(v.w);
        ((ushort4*)d)[i] = o;
    }
}

// ---------------- merged prep: weight cvt + proj transpose + b' -------------
// blocks 0..2047      : fp32->bf16 weight conversion (grid-stride)
// blocks 2048..6143   : proj_W transpose (4,512,2048) f32 -> (4,2048,512) bf16
// blocks 6144..6207   : b' = fuse_b + fuse_W @ proj_b_flat (exact f32)
struct PrepArgs {
    const float* wsrc[6];        // fuse|up|lat|down|out1|out2
    const float* proj_W;
    const float* fuse_W;
    const float* fuse_b;
    const float* proj_b;
    unsigned short* wdst;        // w16
    unsigned short* projT;       // projT16
    float* bp;
};

__global__ __launch_bounds__(256)
void prep_kernel(PrepArgs pa)
{
    __shared__ float t[32][33];
    const int bid = blockIdx.x;
    const int tid = threadIdx.x;

    if (bid < 2048) {
        const int total = 1310720;  // f4 units
        for (int i = bid * 256 + tid; i < total; i += 2048 * 256) {
            const float* sp; int base;
            if      (i <  262144) { sp = pa.wsrc[0]; base = 0;       }
            else if (i <  524288) { sp = pa.wsrc[1]; base = 262144;  }
            else if (i <  786432) { sp = pa.wsrc[2]; base = 524288;  }
            else if (i <  983040) { sp = pa.wsrc[3]; base = 786432;  }
            else if (i < 1048576) { sp = pa.wsrc[4]; base = 983040;  }
            else                  { sp = pa.wsrc[5]; base = 1048576; }
            float4 v = ((const float4*)sp)[i - base];
            ushort4 o;
            o.x = f2bf(v.x); o.y = f2bf(v.y); o.z = f2bf(v.z); o.w = f2bf(v.w);
            ((ushort4*)pa.wdst)[i] = o;
        }
    } else if (bid < 6144) {
        const int b2  = bid - 2048;            // 0..4095
        const int o   = b2 >> 10;
        const int rem = b2 & 1023;
        const int jb  = (rem & 63) * 32;       // col block in 2048
        const int kb  = (rem >> 6) * 32;       // row block in 512
        const int r   = tid >> 3;
        const int c4  = (tid & 7) * 4;
        {
            const float* s = pa.proj_W + ((size_t)o * DCC + kb + r) * DMD + jb + c4;
            float4 v = *(const float4*)s;
            t[r][c4+0]=v.x; t[r][c4+1]=v.y; t[r][c4+2]=v.z; t[r][c4+3]=v.w;
        }
        __syncthreads();
        {
            ushort4 u;
            u.x = f2bf(t[c4+0][r]); u.y = f2bf(t[c4+1][r]);
            u.z = f2bf(t[c4+2][r]); u.w = f2bf(t[c4+3][r]);
            *(ushort4*)(pa.projT + ((size_t)o * DMD + jb + r) * DCC + kb + c4) = u;
        }
    } else {
        const int b3  = bid - 6144;            // 0..63
        const int row = b3 * 8 + (tid >> 5);
        const int l32 = tid & 31;
        const float* r = pa.fuse_W + (size_t)row * (4 * DCC) + l32 * 64;
        const float* p = pa.proj_b + l32 * 64;
        float s = 0.f;
        #pragma unroll
        for (int k = 0; k < 64; k += 4) {
            float4 v = *(const float4*)(r + k);
            float4 q = *(const float4*)(p + k);
            s += v.x*q.x + v.y*q.y + v.z*q.z + v.w*q.w;
        }
        #pragma unroll
        for (int off = 16; off; off >>= 1) s += __shfl_xor(s, off, 64);
        if (l32 == 0) pa.bp[row] = s + pa.fuse_b[row];
    }
}

// ---------------- batched bf16 MFMA GEMM (counted-vmcnt pipeline) -----------
struct GArgs {
    const unsigned short* A[6];
    const unsigned short* W[6];
    const float*          bias[6];
    const float*          add[6];
    void*                 C[6];
};

template<bool OUTF32, bool GELU>
__global__ __launch_bounds__(256)
void gemm16(GArgs ga, int lda, int ldw, int ldadd, int ldc, int K)
{
    __shared__ unsigned short As[3][128 * 32];   // 24 KB
    __shared__ unsigned short Bs[3][128 * 32];   // 24 KB

    const int z    = blockIdx.z;
    const int tid  = threadIdx.x;
    const int wave = tid >> 6;
    const int lane = tid & 63;

    const int nwg   = gridDim.x * gridDim.y;
    const int bid   = blockIdx.y * gridDim.x + blockIdx.x;
    const int swz   = (bid & 7) * (nwg >> 3) + (bid >> 3);
    const int bn    = (swz % gridDim.x) * 128;
    const int bm    = (swz / gridDim.x) * 128;

    const int wr   = wave >> 1;
    const int wc   = wave & 1;

    const unsigned short* Ap = ga.A[z];
    const unsigned short* Wp = ga.W[z];

    const int lrow = lane >> 2;
    const int lcol = (lane & 3) * 8;
    const int l15  = lane & 15;
    const int lh   = lane >> 4;

    f32x4 acc[4][4] = {};

    const int nsteps = K >> 5;

    auto issue = [&](int buf, int k0) {
        #pragma unroll
        for (int r = 0; r < 2; ++r) {
            int c = wave + r * 4;
            async16(Ap + (size_t)(bm + c * 16 + lrow) * lda + k0 + lcol,
                    &As[buf][c * 512]);
            async16(Wp + (size_t)(bn + c * 16 + lrow) * ldw + k0 + lcol,
                    &Bs[buf][c * 512]);
        }
    };

    issue(0, 0);
    issue(1, 32);

    for (int t = 0; t < nsteps; ++t) {
        const int cur = t % 3;
        if (t + 2 < nsteps) issue((t + 2) % 3, (t + 2) * 32);
        const int rem = nsteps - 1 - t;
        if (rem >= 2)      VMCNT(8);
        else if (rem == 1) VMCNT(4);
        else               VMCNT(0);
        __builtin_amdgcn_s_barrier();     // publish buf[cur]

        short8 af[4], bfr[4];
        #pragma unroll
        for (int i = 0; i < 4; ++i) {
            af[i]  = *(const short8*)&As[cur][(wr * 64 + i * 16 + l15) * 32 + lh * 8];
            bfr[i] = *(const short8*)&Bs[cur][(wc * 64 + i * 16 + l15) * 32 + lh * 8];
        }
        __builtin_amdgcn_s_setprio(1);
        #pragma unroll
        for (int mi = 0; mi < 4; ++mi)
            #pragma unroll
            for (int ni = 0; ni < 4; ++ni)
                acc[mi][ni] = __builtin_amdgcn_mfma_f32_16x16x32_bf16(
                    af[mi], bfr[ni], acc[mi][ni], 0, 0, 0);
        __builtin_amdgcn_s_setprio(0);
        __builtin_amdgcn_s_barrier();     // buf[cur] reads done
    }

    const float* bias = ga.bias[z];
    const float* add  = ga.add[z];
    #pragma unroll
    for (int ni = 0; ni < 4; ++ni) {
        int col = bn + wc * 64 + ni * 16 + l15;
        float bv = bias ? bias[col] : 0.0f;
        #pragma unroll
        for (int mi = 0; mi < 4; ++mi) {
            #pragma unroll
            for (int r = 0; r < 4; ++r) {
                int row = bm + wr * 64 + mi * 16 + lh * 4 + r;
                float vv = acc[mi][ni][r] + bv;
                if (GELU) vv = 0.5f * vv * (1.0f + erff(vv * 0.7071067811865475f));
                if (OUTF32) {
                    if (add) vv += add[(size_t)row * ldadd + col];
                    ((float*)ga.C[z])[(size_t)row * ldc + col] = vv;
                } else {
                    ((unsigned short*)ga.C[z])[(size_t)row * ldc + col] = f2bf(vv);
                }
            }
        }
    }
}

// ---------------- x0 reduce: x0 = bf16(sum_o partial_o + b') ----------------
__global__ __launch_bounds__(256)
void x0red(const float* __restrict__ partial, const float* __restrict__ bp,
           unsigned short* __restrict__ x0)
{
    const int i = blockIdx.x * 256 + threadIdx.x;   // f4 units, total 1048576
    float4 a = ((const float4*)partial)[i];
    float4 b = ((const float4*)(partial + TOKH))[i];
    float4 c = ((const float4*)(partial + 2 * (size_t)TOKH))[i];
    float4 d = ((const float4*)(partial + 3 * (size_t)TOKH))[i];
    const int col = (i * 4) & (DCC - 1);
    float4 bv = *(const float4*)(bp + col);
    ushort4 o;
    o.x = f2bf(a.x + b.x + c.x + d.x + bv.x);
    o.y = f2bf(a.y + b.y + c.y + d.y + bv.y);
    o.z = f2bf(a.z + b.z + c.z + d.z + bv.z);
    o.w = f2bf(a.w + b.w + c.w + d.w + bv.w);
    ((ushort4*)x0)[i] = o;
}

// ---------------- fused GEMM + LN (+update), 3-deep counted-vmcnt -----------
// (R14 structure -- best measured; 4-deep was null.)
__device__ inline int csw(int rl, int col) {
    int s = ((rl >> 2) & 3) ^ (rl & 3);
    return rl * 512 + (col ^ (s << 4));
}

template<int MODE>
__global__ __launch_bounds__(512)
void gemm_fused(const unsigned short* __restrict__ Ap,
                const unsigned short* __restrict__ Wp,
                const float* __restrict__ bias,
                const float* __restrict__ g,
                const float* __restrict__ b,
                const unsigned short* a_in,
                const unsigned short* t_in,
                const unsigned short* __restrict__ lat_in,
                const float* __restrict__ logit,
                unsigned short* outp)
{
    __shared__ unsigned short Bs[3][512 * 32];   // 96 KB
    __shared__ unsigned short As3[3][32 * 32];   //  6 KB
    __shared__ float red[2][8][32];              //  2 KB

    const int tid  = threadIdx.x;
    const int wave = tid >> 6;         // 0..7
    const int lane = tid & 63;
    const int lrow = lane >> 2;        // 0..15
    const int lc8  = (lane & 3) * 8;   // 0,8,16,24
    const int bm   = blockIdx.x * 32;
    const int l15  = lane & 15;
    const int lh   = lane >> 4;
    const int c0   = lane * 8;

    f32x4 acc[2][4] = {};

    auto issue = [&](int buf, int k0) {
        if (wave < 2)
            async16(Ap + (size_t)(bm + wave * 16 + lrow) * DCC + k0 + lc8,
                    &As3[buf][wave * 512]);
        #pragma unroll
        for (int r = 0; r < 4; ++r)
            async16(Wp + (size_t)((r * 8 + wave) * 16 + lrow) * DCC + k0 + lc8,
                    &Bs[buf][(r * 8 + wave) * 512]);
    };

    issue(0, 0);
    issue(1, 32);

    #pragma unroll
    for (int t = 0; t < 16; ++t) {
        const int cur = t % 3;
        if (t + 2 < 16) issue((t + 2) % 3, (t + 2) * 32);
        if (t < 14)      { if (wave < 2) VMCNT(10); else VMCNT(8); }
        else if (t == 14){ if (wave < 2) VMCNT(5);  else VMCNT(4); }
        else             { VMCNT(0); }
        __builtin_amdgcn_s_barrier();   // publish buf[cur]
        short8 af[2], bfr[4];
        #pragma unroll
        for (int mi = 0; mi < 2; ++mi)
            af[mi] = *(const short8*)&As3[cur][(mi * 16 + l15) * 32 + lh * 8];
        #pragma unroll
        for (int ni = 0; ni < 4; ++ni)
            bfr[ni] = *(const short8*)&Bs[cur][(wave * 64 + ni * 16 + l15) * 32 + lh * 8];
        __builtin_amdgcn_s_setprio(1);
        #pragma unroll
        for (int mi = 0; mi < 2; ++mi)
            #pragma unroll
            for (int ni = 0; ni < 4; ++ni)
                acc[mi][ni] = __builtin_amdgcn_mfma_f32_16x16x32_bf16(
                    af[mi], bfr[ni], acc[mi][ni], 0, 0, 0);
        __builtin_amdgcn_s_setprio(0);
        __builtin_amdgcn_s_barrier();   // reads of buf[cur] done
    }

    // ---- LN1 row stats in MFMA layout ----
    float bv[4], gv[4], bbv[4];
    #pragma unroll
    for (int ni = 0; ni < 4; ++ni) {
        int col = wave * 64 + ni * 16 + l15;
        bv[ni] = bias[col]; gv[ni] = g[col]; bbv[ni] = b[col];
    }

    float ps[2][4], pq[2][4];
    #pragma unroll
    for (int mi = 0; mi < 2; ++mi)
        #pragma unroll
        for (int rr = 0; rr < 4; ++rr) {
            float s = 0.f, q = 0.f;
            #pragma unroll
            for (int ni = 0; ni < 4; ++ni) {
                float v = acc[mi][ni][rr] + bv[ni];
                acc[mi][ni][rr] = v;
                s += v; q += v * v;
            }
            #pragma unroll
            for (int off = 1; off < 16; off <<= 1) {
                s += __shfl_xor(s, off, 64);
                q += __shfl_xor(q, off, 64);
            }
            ps[mi][rr] = s; pq[mi][rr] = q;
        }
    if (l15 == 0) {
        #pragma unroll
        for (int mi = 0; mi < 2; ++mi)
            #pragma unroll
            for (int rr = 0; rr < 4; ++rr) {
                int rl = mi * 16 + lh * 4 + rr;
                red[0][wave][rl] = ps[mi][rr];
                red[1][wave][rl] = pq[mi][rr];
            }
    }
    __syncthreads();

    // comp = LN1 result -> compS (reuse Bs[0]; K-loop fully done)
    unsigned short* compS = &Bs[0][0];
    #pragma unroll
    for (int mi = 0; mi < 2; ++mi)
        #pragma unroll
        for (int rr = 0; rr < 4; ++rr) {
            int rl = mi * 16 + lh * 4 + rr;
            float s = 0.f, q = 0.f;
            #pragma unroll
            for (int w = 0; w < 8; ++w) { s += red[0][w][rl]; q += red[1][w][rl]; }
            float m1 = s * (1.0f / DCC);
            float r1 = rsqrtf(q * (1.0f / DCC) - m1 * m1 + 1e-5f);
            #pragma unroll
            for (int ni = 0; ni < 4; ++ni) {
                int col = wave * 64 + ni * 16 + l15;
                compS[csw(rl, col)] = f2bf((acc[mi][ni][rr] - m1) * r1 * gv[ni] + bbv[ni]);
            }
        }
    __syncthreads();

    // ---- phase 2: row-mapped (wave owns 4 rows, lane owns 8 contiguous cols)
    if constexpr (MODE == 0) {
        #pragma unroll
        for (int rr = 0; rr < 4; ++rr) {
            const int rl = wave * 4 + rr;
            const size_t gbase = (size_t)(bm + rl) * DCC + c0;
            short8 cm = *(const short8*)&compS[csw(rl, c0)];
            *(short8*)(outp + gbase) = cm;
        }
    } else {
        float gr[8], br[8], pr[8];
        {
            float4 g0 = *(const float4*)(g + c0),     g1 = *(const float4*)(g + c0 + 4);
            float4 b0 = *(const float4*)(b + c0),     b1 = *(const float4*)(b + c0 + 4);
            float4 p0 = *(const float4*)(logit + c0), p1 = *(const float4*)(logit + c0 + 4);
            float gt[8] = {g0.x,g0.y,g0.z,g0.w,g1.x,g1.y,g1.z,g1.w};
            float bt[8] = {b0.x,b0.y,b0.z,b0.w,b1.x,b1.y,b1.z,b1.w};
            float pt[8] = {p0.x,p0.y,p0.z,p0.w,p1.x,p1.y,p1.z,p1.w};
            #pragma unroll
            for (int j = 0; j < 8; ++j) {
                gr[j] = gt[j]; br[j] = bt[j];
                pr[j] = 1.0f / (1.0f + __expf(-pt[j]));
            }
        }
        #pragma unroll
        for (int rr = 0; rr < 4; ++rr) {
            const int rl = wave * 4 + rr;
            const size_t gbase = (size_t)(bm + rl) * DCC + c0;
            short8 cm = *(const short8*)&compS[csw(rl, c0)];
            short8 ar = *(const short8*)(a_in + gbase);
            short8 tr = *(const short8*)(t_in + gbase);
            short8 lr = *(const short8*)(lat_in + gbase);
            float tv[8], s = 0.f, q = 0.f;
            #pragma unroll
            for (int j = 0; j < 8; ++j) {
                float val = bf2f((unsigned short)ar[j])
                          + 0.5f * (bf2f((unsigned short)cm[j]) - bf2f((unsigned short)tr[j])) * pr[j]
                          + 0.1f * bf2f((unsigned short)lr[j]);
                tv[j] = val; s += val; q += val * val;
            }
            #pragma unroll
            for (int off = 1; off < 64; off <<= 1) {
                s += __shfl_xor(s, off, 64);
                q += __shfl_xor(q, off, 64);
            }
            float m2 = s * (1.0f / DCC);
            float r2 = rsqrtf(q * (1.0f / DCC) - m2 * m2 + 1e-5f);
            short8 o;
            #pragma unroll
            for (int j = 0; j < 8; ++j)
                o[j] = (short)f2bf((tv[j] - m2) * r2 * gr[j] + br[j]);
            *(short8*)(outp + gbase) = o;
        }
    }
}

// ---------------------------------------------------------------------------
extern "C" void kernel_launch(void* const* d_in, const int* in_sizes, int n_in,
                              void* d_out, int out_size, void* d_ws, size_t ws_size,
                              hipStream_t stream)
{
    const float* qwen   = (const float*)d_in[0];
    const float* obs    = (const float*)d_in[1];
    const float* proj_W = (const float*)d_in[2];
    const float* proj_b = (const float*)d_in[3];
    const float* fuse_W = (const float*)d_in[4];
    const float* fuse_b = (const float*)d_in[5];
    const float* up_W   = (const float*)d_in[6];
    const float* up_b   = (const float*)d_in[7];
    const float* lat_W  = (const float*)d_in[8];
    const float* lat_b  = (const float*)d_in[9];
    const float* plogit = (const float*)d_in[10];
    const float* ln_g   = (const float*)d_in[11];
    const float* ln_b   = (const float*)d_in[12];
    const float* down_W = (const float*)d_in[13];
    const float* down_b = (const float*)d_in[14];
    const float* out1_W = (const float*)d_in[15];
    const float* out1_b = (const float*)d_in[16];
    const float* out2_W = (const float*)d_in[17];
    const float* out2_b = (const float*)d_in[18];
    float* out = (float*)d_out;

    // ---- ws layout (ushort); footprint 228.6 MB (proven)
    unsigned short* wsu = (unsigned short*)d_ws;
    float*          bp     = (float*)wsu;                  // 512 f32
    unsigned short* h16    = wsu + 2048;                   // head scratch
    unsigned short* M16    = wsu + 8388608;                // (4,512,2048)
    unsigned short* x0b    = wsu + 16777216;
    unsigned short* acts16[4] = {
        wsu + 20971520, wsu + 20971520 + TOKH,
        wsu + 20971520 + 2 * TOKH, wsu + 20971520 + 3 * TOKH };
    unsigned short* w16    = wsu + 37748736;
    unsigned short* fuseW16 = w16;
    unsigned short* upW16   = w16 + 1048576;
    unsigned short* latW16  = w16 + 2097152;
    unsigned short* downW16 = w16 + 3145728;
    unsigned short* out1W16 = w16 + 3932160;
    unsigned short* out2W16 = w16 + 4194304;
    unsigned short* projT16 = wsu + 47185920;              // (4,2048,512)
    unsigned short* obs16   = wsu + 47185920;              // overlays projT16

    // d_out overlays: part32 (front); pred a/b + lat0..3 (settle)
    float*          part32  = (float*)d_out;
    unsigned short* outu = (unsigned short*)d_out;
    unsigned short* pred16a = outu;
    unsigned short* pred16b = outu + TOKH;
    unsigned short* lat16[4] = { outu + 2*TOKH, outu + 3*TOKH, outu + 4*TOKH, outu + 5*TOKH };

    dim3 blk(256);
    dim3 blk512(512);

    // ---- prep: weight cvt + proj transpose + b' in one launch
    {
        PrepArgs pa;
        pa.wsrc[0] = fuse_W; pa.wsrc[1] = up_W;   pa.wsrc[2] = lat_W;
        pa.wsrc[3] = down_W; pa.wsrc[4] = out1_W; pa.wsrc[5] = out2_W;
        pa.proj_W = proj_W; pa.fuse_W = fuse_W; pa.fuse_b = fuse_b;
        pa.proj_b = proj_b;
        pa.wdst = w16; pa.projT = projT16; pa.bp = bp;
        prep_kernel<<<dim3(6208), blk, 0, stream>>>(pa);
    }

    // ---- M_o = fuseW_o @ projW_o  (512x2048 each, K=512); consumes projT16
    {
        GArgs a{};
        for (int o = 0; o < 4; ++o) {
            a.A[o] = fuseW16 + o * DCC;
            a.W[o] = projT16 + (size_t)o * DMD * DCC;
            a.bias[o] = nullptr;
            a.C[o] = M16 + (size_t)o * DCC * DMD;
        }
        gemm16<false, false><<<dim3(DMD/128, DCC/128, 4), blk, 0, stream>>>(
            a, 4 * DCC, DCC, 0, DMD, DCC);
    }

    // ---- obs -> bf16 (one BW-bound pass; overwrites dead projT16 region)
    cvt_kernel<<<dim3(4096), blk, 0, stream>>>(obs, obs16, 16777216);

    // ---- x0 split-K partials: pure-bf16 gemm16, grid 1024 = ~3-4 blocks/CU
    {
        GArgs a{};
        for (int o = 0; o < 4; ++o) {
            a.A[o] = obs16 + (size_t)o * NTOK * DMD;
            a.W[o] = M16 + (size_t)o * DCC * DMD;
            a.bias[o] = nullptr;
            a.add[o]  = nullptr;
            a.C[o] = part32 + (size_t)o * TOKH;
        }
        gemm16<true, false><<<dim3(DCC/128, NTOK/128, 4), blk, 0, stream>>>(
            a, DMD, DMD, 0, DCC, DMD);
    }
    // ---- x0 = bf16(sum partials + b')
    x0red<<<dim3(TOKH/4/256), blk, 0, stream>>>(part32, bp, x0b);

    dim3 fgrid(NTOK / 32);   // 256 blocks = 1 block/CU

    // ---- initial bottom-up pass
    for (int i = 0; i < 4; ++i) {
        gemm_fused<0><<<fgrid, blk512, 0, stream>>>(
            (i == 0) ? x0b : acts16[i - 1],
            upW16 + (size_t)i * DCC * DCC, up_b + i * DCC,
            ln_g + i * DCC, ln_b + i * DCC,
            nullptr, nullptr, nullptr, nullptr, acts16[i]);
    }

    // ---- settling iterations
    for (int s = 0; s < 5; ++s) {
        {
            GArgs a{};
            a.A[0] = acts16[1]; a.W[0] = downW16 + (size_t)1 * DCC * DCC;
            a.bias[0] = down_b + 1 * DCC; a.C[0] = pred16a;
            a.A[1] = acts16[2]; a.W[1] = downW16 + (size_t)2 * DCC * DCC;
            a.bias[1] = down_b + 2 * DCC; a.C[1] = pred16b;
            for (int i = 0; i < 4; ++i) {
                a.A[2 + i] = acts16[i];
                a.W[2 + i] = latW16 + (size_t)i * DCC * DCC;
                a.bias[2 + i] = lat_b + i * DCC;
                a.C[2 + i] = lat16[i];
            }
            gemm16<false, false><<<dim3(DCC/128, NTOK/128, 6), blk, 0, stream>>>(
                a, DCC, DCC, 0, DCC, DCC);
        }
        for (int i = 0; i < 4; ++i) {
            const unsigned short* tgt =
                (i == 0) ? pred16a : (i == 1) ? pred16b : acts16[i];
            gemm_fused<1><<<fgrid, blk512, 0, stream>>>(
                (i == 0) ? x0b : acts16[i - 1],
                upW16 + (size_t)i * DCC * DCC, up_b + i * DCC,
                ln_g + i * DCC, ln_b + i * DCC,
                acts16[i], tgt, lat16[i], plogit + i * DCC, acts16[i]);
        }
    }

    // ---- head
    {
        GArgs a{};
        a.A[0] = acts16[3]; a.W[0] = out1W16; a.bias[0] = out1_b; a.C[0] = h16;
        gemm16<false, true><<<dim3(DCC/128, NTOK/128, 1), blk, 0, stream>>>(
            a, DCC, DCC, 0, DCC, DCC);
    }
    {
        GArgs a{};
        a.A[0] = h16; a.W[0] = out2W16; a.bias[0] = out2_b;
        a.add[0] = qwen; a.C[0] = out;
        gemm16<true, false><<<dim3(DMD/128, NTOK/128, 1), blk, 0, stream>>>(
            a, DCC, DCC, DMD, DMD, DCC);
    }
}

// Round 17
// 1398.629 us; speedup vs baseline: 1.0151x; 1.0100x over previous
//
#include <hip/hip_runtime.h>
#include <hip/hip_bf16.h>
#include <math.h>

#define NTOK 8192     // B*S
#define DMD  2048     // d_model
#define DCC  512      // d_cortical
#define TOKH 4194304  // NTOK*DCC

typedef __attribute__((ext_vector_type(8))) short short8;
typedef __attribute__((ext_vector_type(4))) float f32x4;

// ---------------- helpers ---------------------------------------------------
__device__ inline float bf2f(unsigned short u) {
    union { unsigned int i; float f; } x; x.i = ((unsigned int)u) << 16; return x.f;
}
__device__ inline unsigned short f2bf(float f) {
    union { float f; unsigned int i; } x; x.f = f;
    unsigned int u = x.i;
    return (unsigned short)((u + 0x7fffu + ((u >> 16) & 1u)) >> 16);
}

typedef const __attribute__((address_space(1))) unsigned int* gas1_t;
typedef __attribute__((address_space(3))) unsigned int* las3_t;
__device__ inline void async16(const void* g, void* l) {
    __builtin_amdgcn_global_load_lds(
        (gas1_t)g,
        (las3_t)(unsigned int)(unsigned long long)l, 16, 0, 0);
}

#define VMCNT(N) asm volatile("s_waitcnt vmcnt(" #N ")" ::: "memory")

// ---------------- fp32 -> bf16 bulk conversion (grid-stride) ----------------
__global__ __launch_bounds__(256)
void cvt_kernel(const float* __restrict__ s, unsigned short* __restrict__ d, int n4)
{
    for (int i = blockIdx.x * 256 + threadIdx.x; i < n4; i += gridDim.x * 256) {
        float4 v = ((const float4*)s)[i];
        ushort4 o;
        o.x = f2bf(v.x); o.y = f2bf(v.y); o.z = f2bf(v.z); o.w = f2bf(v.w);
        ((ushort4*)d)[i] = o;
    }
}

// ---------------- merged prep: weight cvt + proj transpose + b' -------------
struct PrepArgs {
    const float* wsrc[6];        // fuse|up|lat|down|out1|out2
    const float* proj_W;
    const float* fuse_W;
    const float* fuse_b;
    const float* proj_b;
    unsigned short* wdst;        // w16
    unsigned short* projT;       // projT16
    float* bp;
};

__global__ __launch_bounds__(256)
void prep_kernel(PrepArgs pa)
{
    __shared__ float t[32][33];
    const int bid = blockIdx.x;
    const int tid = threadIdx.x;

    if (bid < 2048) {
        const int total = 1310720;  // f4 units
        for (int i = bid * 256 + tid; i < total; i += 2048 * 256) {
            const float* sp; int base;
            if      (i <  262144) { sp = pa.wsrc[0]; base = 0;       }
            else if (i <  524288) { sp = pa.wsrc[1]; base = 262144;  }
            else if (i <  786432) { sp = pa.wsrc[2]; base = 524288;  }
            else if (i <  983040) { sp = pa.wsrc[3]; base = 786432;  }
            else if (i < 1048576) { sp = pa.wsrc[4]; base = 983040;  }
            else                  { sp = pa.wsrc[5]; base = 1048576; }
            float4 v = ((const float4*)sp)[i - base];
            ushort4 o;
            o.x = f2bf(v.x); o.y = f2bf(v.y); o.z = f2bf(v.z); o.w = f2bf(v.w);
            ((ushort4*)pa.wdst)[i] = o;
        }
    } else if (bid < 6144) {
        const int b2  = bid - 2048;            // 0..4095
        const int o   = b2 >> 10;
        const int rem = b2 & 1023;
        const int jb  = (rem & 63) * 32;       // col block in 2048
        const int kb  = (rem >> 6) * 32;       // row block in 512
        const int r   = tid >> 3;
        const int c4  = (tid & 7) * 4;
        {
            const float* s = pa.proj_W + ((size_t)o * DCC + kb + r) * DMD + jb + c4;
            float4 v = *(const float4*)s;
            t[r][c4+0]=v.x; t[r][c4+1]=v.y; t[r][c4+2]=v.z; t[r][c4+3]=v.w;
        }
        __syncthreads();
        {
            ushort4 u;
            u.x = f2bf(t[c4+0][r]); u.y = f2bf(t[c4+1][r]);
            u.z = f2bf(t[c4+2][r]); u.w = f2bf(t[c4+3][r]);
            *(ushort4*)(pa.projT + ((size_t)o * DMD + jb + r) * DCC + kb + c4) = u;
        }
    } else {
        const int b3  = bid - 6144;            // 0..63
        const int row = b3 * 8 + (tid >> 5);
        const int l32 = tid & 31;
        const float* r = pa.fuse_W + (size_t)row * (4 * DCC) + l32 * 64;
        const float* p = pa.proj_b + l32 * 64;
        float s = 0.f;
        #pragma unroll
        for (int k = 0; k < 64; k += 4) {
            float4 v = *(const float4*)(r + k);
            float4 q = *(const float4*)(p + k);
            s += v.x*q.x + v.y*q.y + v.z*q.z + v.w*q.w;
        }
        #pragma unroll
        for (int off = 16; off; off >>= 1) s += __shfl_xor(s, off, 64);
        if (l32 == 0) pa.bp[row] = s + pa.fuse_b[row];
    }
}

// ---------------- batched bf16 MFMA GEMM (single-barrier counted-vmcnt) -----
// 3-deep pipeline; issue for buf[(t+2)%3] moved AFTER the publish barrier of
// step t, which makes barrier-2 redundant: all waves' reads of that buffer
// (step t-1) are complete before they arrive at step t's barrier (lgkmcnt
// before MFMA forces ds_read completion). One barrier per K-step.
struct GArgs {
    const unsigned short* A[6];
    const unsigned short* W[6];
    const float*          bias[6];
    const float*          add[6];
    void*                 C[6];
};

template<bool OUTF32, bool GELU>
__global__ __launch_bounds__(256)
void gemm16(GArgs ga, int lda, int ldw, int ldadd, int ldc, int K)
{
    __shared__ unsigned short As[3][128 * 32];   // 24 KB
    __shared__ unsigned short Bs[3][128 * 32];   // 24 KB

    const int z    = blockIdx.z;
    const int tid  = threadIdx.x;
    const int wave = tid >> 6;
    const int lane = tid & 63;

    const int nwg   = gridDim.x * gridDim.y;
    const int bid   = blockIdx.y * gridDim.x + blockIdx.x;
    const int swz   = (bid & 7) * (nwg >> 3) + (bid >> 3);
    const int bn    = (swz % gridDim.x) * 128;
    const int bm    = (swz / gridDim.x) * 128;

    const int wr   = wave >> 1;
    const int wc   = wave & 1;

    const unsigned short* Ap = ga.A[z];
    const unsigned short* Wp = ga.W[z];

    const int lrow = lane >> 2;
    const int lcol = (lane & 3) * 8;
    const int l15  = lane & 15;
    const int lh   = lane >> 4;

    f32x4 acc[4][4] = {};

    const int nsteps = K >> 5;

    auto issue = [&](int buf, int k0) {
        #pragma unroll
        for (int r = 0; r < 2; ++r) {
            int c = wave + r * 4;
            async16(Ap + (size_t)(bm + c * 16 + lrow) * lda + k0 + lcol,
                    &As[buf][c * 512]);
            async16(Wp + (size_t)(bn + c * 16 + lrow) * ldw + k0 + lcol,
                    &Bs[buf][c * 512]);
        }
    };

    issue(0, 0);
    issue(1, 32);

    for (int t = 0; t < nsteps; ++t) {
        const int cur = t % 3;
        // own batch complete; at most 1 younger batch (4 loads) in flight
        if (t < nsteps - 1) VMCNT(4);
        else                VMCNT(0);
        __builtin_amdgcn_s_barrier();     // publish buf[cur]
        if (t + 2 < nsteps) issue((t + 2) % 3, (t + 2) * 32);

        short8 af[4], bfr[4];
        #pragma unroll
        for (int i = 0; i < 4; ++i) {
            af[i]  = *(const short8*)&As[cur][(wr * 64 + i * 16 + l15) * 32 + lh * 8];
            bfr[i] = *(const short8*)&Bs[cur][(wc * 64 + i * 16 + l15) * 32 + lh * 8];
        }
        __builtin_amdgcn_s_setprio(1);
        #pragma unroll
        for (int mi = 0; mi < 4; ++mi)
            #pragma unroll
            for (int ni = 0; ni < 4; ++ni)
                acc[mi][ni] = __builtin_amdgcn_mfma_f32_16x16x32_bf16(
                    af[mi], bfr[ni], acc[mi][ni], 0, 0, 0);
        __builtin_amdgcn_s_setprio(0);
    }

    const float* bias = ga.bias[z];
    const float* add  = ga.add[z];
    #pragma unroll
    for (int ni = 0; ni < 4; ++ni) {
        int col = bn + wc * 64 + ni * 16 + l15;
        float bv = bias ? bias[col] : 0.0f;
        #pragma unroll
        for (int mi = 0; mi < 4; ++mi) {
            #pragma unroll
            for (int r = 0; r < 4; ++r) {
                int row = bm + wr * 64 + mi * 16 + lh * 4 + r;
                float vv = acc[mi][ni][r] + bv;
                if (GELU) vv = 0.5f * vv * (1.0f + erff(vv * 0.7071067811865475f));
                if (OUTF32) {
                    if (add) vv += add[(size_t)row * ldadd + col];
                    ((float*)ga.C[z])[(size_t)row * ldc + col] = vv;
                } else {
                    ((unsigned short*)ga.C[z])[(size_t)row * ldc + col] = f2bf(vv);
                }
            }
        }
    }
}

// ---------------- x0 reduce: x0 = bf16(sum_o partial_o + b') ----------------
__global__ __launch_bounds__(256)
void x0red(const float* __restrict__ partial, const float* __restrict__ bp,
           unsigned short* __restrict__ x0)
{
    const int i = blockIdx.x * 256 + threadIdx.x;   // f4 units, total 1048576
    float4 a = ((const float4*)partial)[i];
    float4 b = ((const float4*)(partial + TOKH))[i];
    float4 c = ((const float4*)(partial + 2 * (size_t)TOKH))[i];
    float4 d = ((const float4*)(partial + 3 * (size_t)TOKH))[i];
    const int col = (i * 4) & (DCC - 1);
    float4 bv = *(const float4*)(bp + col);
    ushort4 o;
    o.x = f2bf(a.x + b.x + c.x + d.x + bv.x);
    o.y = f2bf(a.y + b.y + c.y + d.y + bv.y);
    o.z = f2bf(a.z + b.z + c.z + d.z + bv.z);
    o.w = f2bf(a.w + b.w + c.w + d.w + bv.w);
    ((ushort4*)x0)[i] = o;
}

// ---------------- fused GEMM + LN (+update), single-barrier pipeline --------
__device__ inline int csw(int rl, int col) {
    int s = ((rl >> 2) & 3) ^ (rl & 3);
    return rl * 512 + (col ^ (s << 4));
}

template<int MODE>
__global__ __launch_bounds__(512)
void gemm_fused(const unsigned short* __restrict__ Ap,
                const unsigned short* __restrict__ Wp,
                const float* __restrict__ bias,
                const float* __restrict__ g,
                const float* __restrict__ b,
                const unsigned short* a_in,
                const unsigned short* t_in,
                const unsigned short* __restrict__ lat_in,
                const float* __restrict__ logit,
                unsigned short* outp)
{
    __shared__ unsigned short Bs[3][512 * 32];   // 96 KB
    __shared__ unsigned short As3[3][32 * 32];   //  6 KB
    __shared__ float red[2][8][32];              //  2 KB

    const int tid  = threadIdx.x;
    const int wave = tid >> 6;         // 0..7
    const int lane = tid & 63;
    const int lrow = lane >> 2;        // 0..15
    const int lc8  = (lane & 3) * 8;   // 0,8,16,24
    const int bm   = blockIdx.x * 32;
    const int l15  = lane & 15;
    const int lh   = lane >> 4;
    const int c0   = lane * 8;

    f32x4 acc[2][4] = {};

    auto issue = [&](int buf, int k0) {
        if (wave < 2)
            async16(Ap + (size_t)(bm + wave * 16 + lrow) * DCC + k0 + lc8,
                    &As3[buf][wave * 512]);
        #pragma unroll
        for (int r = 0; r < 4; ++r)
            async16(Wp + (size_t)((r * 8 + wave) * 16 + lrow) * DCC + k0 + lc8,
                    &Bs[buf][(r * 8 + wave) * 512]);
    };

    issue(0, 0);
    issue(1, 32);

    #pragma unroll
    for (int t = 0; t < 16; ++t) {
        const int cur = t % 3;
        // own batch complete; at most 1 younger batch in flight
        if (t < 15) { if (wave < 2) VMCNT(5); else VMCNT(4); }
        else        { VMCNT(0); }
        __builtin_amdgcn_s_barrier();   // publish buf[cur]
        if (t + 2 < 16) issue((t + 2) % 3, (t + 2) * 32);

        short8 af[2], bfr[4];
        #pragma unroll
        for (int mi = 0; mi < 2; ++mi)
            af[mi] = *(const short8*)&As3[cur][(mi * 16 + l15) * 32 + lh * 8];
        #pragma unroll
        for (int ni = 0; ni < 4; ++ni)
            bfr[ni] = *(const short8*)&Bs[cur][(wave * 64 + ni * 16 + l15) * 32 + lh * 8];
        __builtin_amdgcn_s_setprio(1);
        #pragma unroll
        for (int mi = 0; mi < 2; ++mi)
            #pragma unroll
            for (int ni = 0; ni < 4; ++ni)
                acc[mi][ni] = __builtin_amdgcn_mfma_f32_16x16x32_bf16(
                    af[mi], bfr[ni], acc[mi][ni], 0, 0, 0);
        __builtin_amdgcn_s_setprio(0);
    }

    // ---- LN1 row stats in MFMA layout ----
    float bv[4], gv[4], bbv[4];
    #pragma unroll
    for (int ni = 0; ni < 4; ++ni) {
        int col = wave * 64 + ni * 16 + l15;
        bv[ni] = bias[col]; gv[ni] = g[col]; bbv[ni] = b[col];
    }

    float ps[2][4], pq[2][4];
    #pragma unroll
    for (int mi = 0; mi < 2; ++mi)
        #pragma unroll
        for (int rr = 0; rr < 4; ++rr) {
            float s = 0.f, q = 0.f;
            #pragma unroll
            for (int ni = 0; ni < 4; ++ni) {
                float v = acc[mi][ni][rr] + bv[ni];
                acc[mi][ni][rr] = v;
                s += v; q += v * v;
            }
            #pragma unroll
            for (int off = 1; off < 16; off <<= 1) {
                s += __shfl_xor(s, off, 64);
                q += __shfl_xor(q, off, 64);
            }
            ps[mi][rr] = s; pq[mi][rr] = q;
        }
    if (l15 == 0) {
        #pragma unroll
        for (int mi = 0; mi < 2; ++mi)
            #pragma unroll
            for (int rr = 0; rr < 4; ++rr) {
                int rl = mi * 16 + lh * 4 + rr;
                red[0][wave][rl] = ps[mi][rr];
                red[1][wave][rl] = pq[mi][rr];
            }
    }
    __syncthreads();

    // comp = LN1 result -> compS (reuse Bs[0]; K-loop fully done)
    unsigned short* compS = &Bs[0][0];
    #pragma unroll
    for (int mi = 0; mi < 2; ++mi)
        #pragma unroll
        for (int rr = 0; rr < 4; ++rr) {
            int rl = mi * 16 + lh * 4 + rr;
            float s = 0.f, q = 0.f;
            #pragma unroll
            for (int w = 0; w < 8; ++w) { s += red[0][w][rl]; q += red[1][w][rl]; }
            float m1 = s * (1.0f / DCC);
            float r1 = rsqrtf(q * (1.0f / DCC) - m1 * m1 + 1e-5f);
            #pragma unroll
            for (int ni = 0; ni < 4; ++ni) {
                int col = wave * 64 + ni * 16 + l15;
                compS[csw(rl, col)] = f2bf((acc[mi][ni][rr] - m1) * r1 * gv[ni] + bbv[ni]);
            }
        }
    __syncthreads();

    // ---- phase 2: row-mapped (wave owns 4 rows, lane owns 8 contiguous cols)
    if constexpr (MODE == 0) {
        #pragma unroll
        for (int rr = 0; rr < 4; ++rr) {
            const int rl = wave * 4 + rr;
            const size_t gbase = (size_t)(bm + rl) * DCC + c0;
            short8 cm = *(const short8*)&compS[csw(rl, c0)];
            *(short8*)(outp + gbase) = cm;
        }
    } else {
        float gr[8], br[8], pr[8];
        {
            float4 g0 = *(const float4*)(g + c0),     g1 = *(const float4*)(g + c0 + 4);
            float4 b0 = *(const float4*)(b + c0),     b1 = *(const float4*)(b + c0 + 4);
            float4 p0 = *(const float4*)(logit + c0), p1 = *(const float4*)(logit + c0 + 4);
            float gt[8] = {g0.x,g0.y,g0.z,g0.w,g1.x,g1.y,g1.z,g1.w};
            float bt[8] = {b0.x,b0.y,b0.z,b0.w,b1.x,b1.y,b1.z,b1.w};
            float pt[8] = {p0.x,p0.y,p0.z,p0.w,p1.x,p1.y,p1.z,p1.w};
            #pragma unroll
            for (int j = 0; j < 8; ++j) {
                gr[j] = gt[j]; br[j] = bt[j];
                pr[j] = 1.0f / (1.0f + __expf(-pt[j]));
            }
        }
        #pragma unroll
        for (int rr = 0; rr < 4; ++rr) {
            const int rl = wave * 4 + rr;
            const size_t gbase = (size_t)(bm + rl) * DCC + c0;
            short8 cm = *(const short8*)&compS[csw(rl, c0)];
            short8 ar = *(const short8*)(a_in + gbase);
            short8 tr = *(const short8*)(t_in + gbase);
            short8 lr = *(const short8*)(lat_in + gbase);
            float tv[8], s = 0.f, q = 0.f;
            #pragma unroll
            for (int j = 0; j < 8; ++j) {
                float val = bf2f((unsigned short)ar[j])
                          + 0.5f * (bf2f((unsigned short)cm[j]) - bf2f((unsigned short)tr[j])) * pr[j]
                          + 0.1f * bf2f((unsigned short)lr[j]);
                tv[j] = val; s += val; q += val * val;
            }
            #pragma unroll
            for (int off = 1; off < 64; off <<= 1) {
                s += __shfl_xor(s, off, 64);
                q += __shfl_xor(q, off, 64);
            }
            float m2 = s * (1.0f / DCC);
            float r2 = rsqrtf(q * (1.0f / DCC) - m2 * m2 + 1e-5f);
            short8 o;
            #pragma unroll
            for (int j = 0; j < 8; ++j)
                o[j] = (short)f2bf((tv[j] - m2) * r2 * gr[j] + br[j]);
            *(short8*)(outp + gbase) = o;
        }
    }
}

// ---------------------------------------------------------------------------
extern "C" void kernel_launch(void* const* d_in, const int* in_sizes, int n_in,
                              void* d_out, int out_size, void* d_ws, size_t ws_size,
                              hipStream_t stream)
{
    const float* qwen   = (const float*)d_in[0];
    const float* obs    = (const float*)d_in[1];
    const float* proj_W = (const float*)d_in[2];
    const float* proj_b = (const float*)d_in[3];
    const float* fuse_W = (const float*)d_in[4];
    const float* fuse_b = (const float*)d_in[5];
    const float* up_W   = (const float*)d_in[6];
    const float* up_b   = (const float*)d_in[7];
    const float* lat_W  = (const float*)d_in[8];
    const float* lat_b  = (const float*)d_in[9];
    const float* plogit = (const float*)d_in[10];
    const float* ln_g   = (const float*)d_in[11];
    const float* ln_b   = (const float*)d_in[12];
    const float* down_W = (const float*)d_in[13];
    const float* down_b = (const float*)d_in[14];
    const float* out1_W = (const float*)d_in[15];
    const float* out1_b = (const float*)d_in[16];
    const float* out2_W = (const float*)d_in[17];
    const float* out2_b = (const float*)d_in[18];
    float* out = (float*)d_out;

    // ---- ws layout (ushort); footprint 228.6 MB (proven)
    unsigned short* wsu = (unsigned short*)d_ws;
    float*          bp     = (float*)wsu;                  // 512 f32
    unsigned short* h16    = wsu + 2048;                   // head scratch
    unsigned short* M16    = wsu + 8388608;                // (4,512,2048)
    unsigned short* x0b    = wsu + 16777216;
    unsigned short* acts16[4] = {
        wsu + 20971520, wsu + 20971520 + TOKH,
        wsu + 20971520 + 2 * TOKH, wsu + 20971520 + 3 * TOKH };
    unsigned short* w16    = wsu + 37748736;
    unsigned short* fuseW16 = w16;
    unsigned short* upW16   = w16 + 1048576;
    unsigned short* latW16  = w16 + 2097152;
    unsigned short* downW16 = w16 + 3145728;
    unsigned short* out1W16 = w16 + 3932160;
    unsigned short* out2W16 = w16 + 4194304;
    unsigned short* projT16 = wsu + 47185920;              // (4,2048,512)
    unsigned short* obs16   = wsu + 47185920;              // overlays projT16

    // d_out overlays: part32 (front); pred a/b + lat0..3 (settle)
    float*          part32  = (float*)d_out;
    unsigned short* outu = (unsigned short*)d_out;
    unsigned short* pred16a = outu;
    unsigned short* pred16b = outu + TOKH;
    unsigned short* lat16[4] = { outu + 2*TOKH, outu + 3*TOKH, outu + 4*TOKH, outu + 5*TOKH };

    dim3 blk(256);
    dim3 blk512(512);

    // ---- prep: weight cvt + proj transpose + b' in one launch
    {
        PrepArgs pa;
        pa.wsrc[0] = fuse_W; pa.wsrc[1] = up_W;   pa.wsrc[2] = lat_W;
        pa.wsrc[3] = down_W; pa.wsrc[4] = out1_W; pa.wsrc[5] = out2_W;
        pa.proj_W = proj_W; pa.fuse_W = fuse_W; pa.fuse_b = fuse_b;
        pa.proj_b = proj_b;
        pa.wdst = w16; pa.projT = projT16; pa.bp = bp;
        prep_kernel<<<dim3(6208), blk, 0, stream>>>(pa);
    }

    // ---- M_o = fuseW_o @ projW_o  (512x2048 each, K=512); consumes projT16
    {
        GArgs a{};
        for (int o = 0; o < 4; ++o) {
            a.A[o] = fuseW16 + o * DCC;
            a.W[o] = projT16 + (size_t)o * DMD * DCC;
            a.bias[o] = nullptr;
            a.C[o] = M16 + (size_t)o * DCC * DMD;
        }
        gemm16<false, false><<<dim3(DMD/128, DCC/128, 4), blk, 0, stream>>>(
            a, 4 * DCC, DCC, 0, DMD, DCC);
    }

    // ---- obs -> bf16 (one BW-bound pass; overwrites dead projT16 region)
    cvt_kernel<<<dim3(4096), blk, 0, stream>>>(obs, obs16, 16777216);

    // ---- x0 split-K partials: pure-bf16 gemm16, grid 1024 = ~3-4 blocks/CU
    {
        GArgs a{};
        for (int o = 0; o < 4; ++o) {
            a.A[o] = obs16 + (size_t)o * NTOK * DMD;
            a.W[o] = M16 + (size_t)o * DCC * DMD;
            a.bias[o] = nullptr;
            a.add[o]  = nullptr;
            a.C[o] = part32 + (size_t)o * TOKH;
        }
        gemm16<true, false><<<dim3(DCC/128, NTOK/128, 4), blk, 0, stream>>>(
            a, DMD, DMD, 0, DCC, DMD);
    }
    // ---- x0 = bf16(sum partials + b')
    x0red<<<dim3(TOKH/4/256), blk, 0, stream>>>(part32, bp, x0b);

    dim3 fgrid(NTOK / 32);   // 256 blocks = 1 block/CU

    // ---- initial bottom-up pass
    for (int i = 0; i < 4; ++i) {
        gemm_fused<0><<<fgrid, blk512, 0, stream>>>(
            (i == 0) ? x0b : acts16[i - 1],
            upW16 + (size_t)i * DCC * DCC, up_b + i * DCC,
            ln_g + i * DCC, ln_b + i * DCC,
            nullptr, nullptr, nullptr, nullptr, acts16[i]);
    }

    // ---- settling iterations
    for (int s = 0; s < 5; ++s) {
        {
            GArgs a{};
            a.A[0] = acts16[1]; a.W[0] = downW16 + (size_t)1 * DCC * DCC;
            a.bias[0] = down_b + 1 * DCC; a.C[0] = pred16a;
            a.A[1] = acts16[2]; a.W[1] = downW16 + (size_t)2 * DCC * DCC;
            a.bias[1] = down_b + 2 * DCC; a.C[1] = pred16b;
            for (int i = 0; i < 4; ++i) {
                a.A[2 + i] = acts16[i];
                a.W[2 + i] = latW16 + (size_t)i * DCC * DCC;
                a.bias[2 + i] = lat_b + i * DCC;
                a.C[2 + i] = lat16[i];
            }
            gemm16<false, false><<<dim3(DCC/128, NTOK/128, 6), blk, 0, stream>>>(
                a, DCC, DCC, 0, DCC, DCC);
        }
        for (int i = 0; i < 4; ++i) {
            const unsigned short* tgt =
                (i == 0) ? pred16a : (i == 1) ? pred16b : acts16[i];
            gemm_fused<1><<<fgrid, blk512, 0, stream>>>(
                (i == 0) ? x0b : acts16[i - 1],
                upW16 + (size_t)i * DCC * DCC, up_b + i * DCC,
                ln_g + i * DCC, ln_b + i * DCC,
                acts16[i], tgt, lat16[i], plogit + i * DCC, acts16[i]);
        }
    }

    // ---- head
    {
        GArgs a{};
        a.A[0] = acts16[3]; a.W[0] = out1W16; a.bias[0] = out1_b; a.C[0] = h16;
        gemm16<false, true><<<dim3(DCC/128, NTOK/128, 1), blk, 0, stream>>>(
            a, DCC, DCC, 0, DCC, DCC);
    }
    {
        GArgs a{};
        a.A[0] = h16; a.W[0] = out2W16; a.bias[0] = out2_b;
        a.add[0] = qwen; a.C[0] = out;
        gemm16<true, false><<<dim3(DMD/128, NTOK/128, 1), blk, 0, stream>>>(
            a, DCC, DCC, DMD, DMD, DCC);
    }
}

// Round 18
// 1344.789 us; speedup vs baseline: 1.0557x; 1.0400x over previous
//
#include <hip/hip_runtime.h>
#include <hip/hip_bf16.h>
#include <math.h>

#define NTOK 8192     // B*S
#define DMD  2048     // d_model
#define DCC  512      // d_cortical
#define TOKH 4194304  // NTOK*DCC

typedef __attribute__((ext_vector_type(8))) short short8;
typedef __attribute__((ext_vector_type(4))) float f32x4;

// ---------------- helpers ---------------------------------------------------
__device__ inline float bf2f(unsigned short u) {
    union { unsigned int i; float f; } x; x.i = ((unsigned int)u) << 16; return x.f;
}
__device__ inline unsigned short f2bf(float f) {
    union { float f; unsigned int i; } x; x.f = f;
    unsigned int u = x.i;
    return (unsigned short)((u + 0x7fffu + ((u >> 16) & 1u)) >> 16);
}

typedef const __attribute__((address_space(1))) unsigned int* gas1_t;
typedef __attribute__((address_space(3))) unsigned int* las3_t;
__device__ inline void async16(const void* g, void* l) {
    __builtin_amdgcn_global_load_lds(
        (gas1_t)g,
        (las3_t)(unsigned int)(unsigned long long)l, 16, 0, 0);
}

#define VMCNT(N) asm volatile("s_waitcnt vmcnt(" #N ")" ::: "memory")

// ---------------- fp32 -> bf16 bulk conversion (grid-stride) ----------------
__global__ __launch_bounds__(256)
void cvt_kernel(const float* __restrict__ s, unsigned short* __restrict__ d, int n4)
{
    for (int i = blockIdx.x * 256 + threadIdx.x; i < n4; i += gridDim.x * 256) {
        float4 v = ((const float4*)s)[i];
        ushort4 o;
        o.x = f2bf(v.x); o.y = f2bf(v.y); o.z = f2bf(v.z); o.w = f2bf(v.w);
        ((ushort4*)d)[i] = o;
    }
}

// ---------------- merged prep: weight cvt + proj transpose + b' -------------
struct PrepArgs {
    const float* wsrc[6];        // fuse|up|lat|down|out1|out2
    const float* proj_W;
    const float* fuse_W;
    const float* fuse_b;
    const float* proj_b;
    unsigned short* wdst;        // w16
    unsigned short* projT;       // projT16
    float* bp;
};

__global__ __launch_bounds__(256)
void prep_kernel(PrepArgs pa)
{
    __shared__ float t[32][33];
    const int bid = blockIdx.x;
    const int tid = threadIdx.x;

    if (bid < 2048) {
        const int total = 1310720;  // f4 units
        for (int i = bid * 256 + tid; i < total; i += 2048 * 256) {
            const float* sp; int base;
            if      (i <  262144) { sp = pa.wsrc[0]; base = 0;       }
            else if (i <  524288) { sp = pa.wsrc[1]; base = 262144;  }
            else if (i <  786432) { sp = pa.wsrc[2]; base = 524288;  }
            else if (i <  983040) { sp = pa.wsrc[3]; base = 786432;  }
            else if (i < 1048576) { sp = pa.wsrc[4]; base = 983040;  }
            else                  { sp = pa.wsrc[5]; base = 1048576; }
            float4 v = ((const float4*)sp)[i - base];
            ushort4 o;
            o.x = f2bf(v.x); o.y = f2bf(v.y); o.z = f2bf(v.z); o.w = f2bf(v.w);
            ((ushort4*)pa.wdst)[i] = o;
        }
    } else if (bid < 6144) {
        const int b2  = bid - 2048;            // 0..4095
        const int o   = b2 >> 10;
        const int rem = b2 & 1023;
        const int jb  = (rem & 63) * 32;       // col block in 2048
        const int kb  = (rem >> 6) * 32;       // row block in 512
        const int r   = tid >> 3;
        const int c4  = (tid & 7) * 4;
        {
            const float* s = pa.proj_W + ((size_t)o * DCC + kb + r) * DMD + jb + c4;
            float4 v = *(const float4*)s;
            t[r][c4+0]=v.x; t[r][c4+1]=v.y; t[r][c4+2]=v.z; t[r][c4+3]=v.w;
        }
        __syncthreads();
        {
            ushort4 u;
            u.x = f2bf(t[c4+0][r]); u.y = f2bf(t[c4+1][r]);
            u.z = f2bf(t[c4+2][r]); u.w = f2bf(t[c4+3][r]);
            *(ushort4*)(pa.projT + ((size_t)o * DMD + jb + r) * DCC + kb + c4) = u;
        }
    } else {
        const int b3  = bid - 6144;            // 0..63
        const int row = b3 * 8 + (tid >> 5);
        const int l32 = tid & 31;
        const float* r = pa.fuse_W + (size_t)row * (4 * DCC) + l32 * 64;
        const float* p = pa.proj_b + l32 * 64;
        float s = 0.f;
        #pragma unroll
        for (int k = 0; k < 64; k += 4) {
            float4 v = *(const float4*)(r + k);
            float4 q = *(const float4*)(p + k);
            s += v.x*q.x + v.y*q.y + v.z*q.z + v.w*q.w;
        }
        #pragma unroll
        for (int off = 16; off; off >>= 1) s += __shfl_xor(s, off, 64);
        if (l32 == 0) pa.bp[row] = s + pa.fuse_b[row];
    }
}

// ---------------- batched bf16 MFMA GEMM (single-barrier counted-vmcnt) -----
struct GArgs {
    const unsigned short* A[6];
    const unsigned short* W[6];
    const float*          bias[6];
    const float*          add[6];
    void*                 C[6];
};

template<bool OUTF32, bool GELU>
__global__ __launch_bounds__(256)
void gemm16(GArgs ga, int lda, int ldw, int ldadd, int ldc, int K)
{
    __shared__ unsigned short As[3][128 * 32];   // 24 KB
    __shared__ unsigned short Bs[3][128 * 32];   // 24 KB

    const int z    = blockIdx.z;
    const int tid  = threadIdx.x;
    const int wave = tid >> 6;
    const int lane = tid & 63;

    const int nwg   = gridDim.x * gridDim.y;
    const int bid   = blockIdx.y * gridDim.x + blockIdx.x;
    const int swz   = (bid & 7) * (nwg >> 3) + (bid >> 3);
    const int bn    = (swz % gridDim.x) * 128;
    const int bm    = (swz / gridDim.x) * 128;

    const int wr   = wave >> 1;
    const int wc   = wave & 1;

    const unsigned short* Ap = ga.A[z];
    const unsigned short* Wp = ga.W[z];

    const int lrow = lane >> 2;
    const int lcol = (lane & 3) * 8;
    const int l15  = lane & 15;
    const int lh   = lane >> 4;

    f32x4 acc[4][4] = {};

    const int nsteps = K >> 5;

    auto issue = [&](int buf, int k0) {
        #pragma unroll
        for (int r = 0; r < 2; ++r) {
            int c = wave + r * 4;
            async16(Ap + (size_t)(bm + c * 16 + lrow) * lda + k0 + lcol,
                    &As[buf][c * 512]);
            async16(Wp + (size_t)(bn + c * 16 + lrow) * ldw + k0 + lcol,
                    &Bs[buf][c * 512]);
        }
    };

    issue(0, 0);
    issue(1, 32);

    for (int t = 0; t < nsteps; ++t) {
        const int cur = t % 3;
        if (t < nsteps - 1) VMCNT(4);
        else                VMCNT(0);
        __builtin_amdgcn_s_barrier();     // publish buf[cur]
        if (t + 2 < nsteps) issue((t + 2) % 3, (t + 2) * 32);

        short8 af[4], bfr[4];
        #pragma unroll
        for (int i = 0; i < 4; ++i) {
            af[i]  = *(const short8*)&As[cur][(wr * 64 + i * 16 + l15) * 32 + lh * 8];
            bfr[i] = *(const short8*)&Bs[cur][(wc * 64 + i * 16 + l15) * 32 + lh * 8];
        }
        __builtin_amdgcn_s_setprio(1);
        #pragma unroll
        for (int mi = 0; mi < 4; ++mi)
            #pragma unroll
            for (int ni = 0; ni < 4; ++ni)
                acc[mi][ni] = __builtin_amdgcn_mfma_f32_16x16x32_bf16(
                    af[mi], bfr[ni], acc[mi][ni], 0, 0, 0);
        __builtin_amdgcn_s_setprio(0);
    }

    const float* bias = ga.bias[z];
    const float* add  = ga.add[z];
    #pragma unroll
    for (int ni = 0; ni < 4; ++ni) {
        int col = bn + wc * 64 + ni * 16 + l15;
        float bv = bias ? bias[col] : 0.0f;
        #pragma unroll
        for (int mi = 0; mi < 4; ++mi) {
            #pragma unroll
            for (int r = 0; r < 4; ++r) {
                int row = bm + wr * 64 + mi * 16 + lh * 4 + r;
                float vv = acc[mi][ni][r] + bv;
                if (GELU) vv = 0.5f * vv * (1.0f + erff(vv * 0.7071067811865475f));
                if (OUTF32) {
                    if (add) vv += add[(size_t)row * ldadd + col];
                    ((float*)ga.C[z])[(size_t)row * ldc + col] = vv;
                } else {
                    ((unsigned short*)ga.C[z])[(size_t)row * ldc + col] = f2bf(vv);
                }
            }
        }
    }
}

// ---------------- x0 reduce: x0 = bf16(sum_o partial_o + b') ----------------
__global__ __launch_bounds__(256)
void x0red(const float* __restrict__ partial, const float* __restrict__ bp,
           unsigned short* __restrict__ x0)
{
    const int i = blockIdx.x * 256 + threadIdx.x;   // f4 units, total 1048576
    float4 a = ((const float4*)partial)[i];
    float4 b = ((const float4*)(partial + TOKH))[i];
    float4 c = ((const float4*)(partial + 2 * (size_t)TOKH))[i];
    float4 d = ((const float4*)(partial + 3 * (size_t)TOKH))[i];
    const int col = (i * 4) & (DCC - 1);
    float4 bv = *(const float4*)(bp + col);
    ushort4 o;
    o.x = f2bf(a.x + b.x + c.x + d.x + bv.x);
    o.y = f2bf(a.y + b.y + c.y + d.y + bv.y);
    o.z = f2bf(a.z + b.z + c.z + d.z + bv.z);
    o.w = f2bf(a.w + b.w + c.w + d.w + bv.w);
    ((ushort4*)x0)[i] = o;
}

// ---------------- paired fused kernel: two serial layers in one launch ------
// Layer A (first): up-GEMM from global Ap; LN1 -> xS; update (MODE1) or copy
// (MODE0); new acts written to global out0 AND kept in xS (csw layout).
// Layer B (second): up-GEMM with A-fragments read DIRECTLY FROM xS (no global
// A staging -- the acts round-trip and one launch gap are eliminated); LN1;
// update/copy; write out1. Single-barrier 3-deep counted-vmcnt K-loops.
// LDS: Bs 3x32K + As3 3x2K + xS 32K + red 2K = 136 KB (1 block/CU, grid-capped).
__device__ inline int csw(int rl, int col) {
    int s = ((rl >> 2) & 3) ^ (rl & 3);
    return rl * 512 + (col ^ (s << 4));
}

template<int MODE>
__global__ __launch_bounds__(512)
void gemm_fused2(const unsigned short* __restrict__ Ap,
                 const unsigned short* __restrict__ W0,
                 const float* __restrict__ bias0,
                 const float* __restrict__ g0,
                 const float* __restrict__ b0,
                 const unsigned short* a0,
                 const unsigned short* t0,
                 const unsigned short* __restrict__ lat0,
                 const float* __restrict__ logit0,
                 unsigned short* out0,
                 const unsigned short* __restrict__ W1,
                 const float* __restrict__ bias1,
                 const float* __restrict__ g1,
                 const float* __restrict__ b1,
                 const unsigned short* a1,
                 const unsigned short* t1,
                 const unsigned short* __restrict__ lat1,
                 const float* __restrict__ logit1,
                 unsigned short* out1)
{
    __shared__ unsigned short Bs[3][512 * 32];   // 96 KB
    __shared__ unsigned short As3[3][32 * 32];   //  6 KB
    __shared__ unsigned short xS[32 * 512];      // 32 KB
    __shared__ float red[2][8][32];              //  2 KB

    const int tid  = threadIdx.x;
    const int wave = tid >> 6;         // 0..7
    const int lane = tid & 63;
    const int lrow = lane >> 2;        // 0..15
    const int lc8  = (lane & 3) * 8;   // 0,8,16,24
    const int bm   = blockIdx.x * 32;
    const int l15  = lane & 15;
    const int lh   = lane >> 4;
    const int c0   = lane * 8;

    f32x4 acc[2][4];

    // ---- LN1 stats + comp -> xS (shared by both layers) --------------------
    auto ln1_to_xS = [&](const float* bias, const float* g, const float* b) {
        float bv[4], gv[4], bbv[4];
        #pragma unroll
        for (int ni = 0; ni < 4; ++ni) {
            int col = wave * 64 + ni * 16 + l15;
            bv[ni] = bias[col]; gv[ni] = g[col]; bbv[ni] = b[col];
        }
        float ps[2][4], pq[2][4];
        #pragma unroll
        for (int mi = 0; mi < 2; ++mi)
            #pragma unroll
            for (int rr = 0; rr < 4; ++rr) {
                float s = 0.f, q = 0.f;
                #pragma unroll
                for (int ni = 0; ni < 4; ++ni) {
                    float v = acc[mi][ni][rr] + bv[ni];
                    acc[mi][ni][rr] = v;
                    s += v; q += v * v;
                }
                #pragma unroll
                for (int off = 1; off < 16; off <<= 1) {
                    s += __shfl_xor(s, off, 64);
                    q += __shfl_xor(q, off, 64);
                }
                ps[mi][rr] = s; pq[mi][rr] = q;
            }
        if (l15 == 0) {
            #pragma unroll
            for (int mi = 0; mi < 2; ++mi)
                #pragma unroll
                for (int rr = 0; rr < 4; ++rr) {
                    int rl = mi * 16 + lh * 4 + rr;
                    red[0][wave][rl] = ps[mi][rr];
                    red[1][wave][rl] = pq[mi][rr];
                }
        }
        __syncthreads();
        #pragma unroll
        for (int mi = 0; mi < 2; ++mi)
            #pragma unroll
            for (int rr = 0; rr < 4; ++rr) {
                int rl = mi * 16 + lh * 4 + rr;
                float s = 0.f, q = 0.f;
                #pragma unroll
                for (int w = 0; w < 8; ++w) { s += red[0][w][rl]; q += red[1][w][rl]; }
                float m1 = s * (1.0f / DCC);
                float r1 = rsqrtf(q * (1.0f / DCC) - m1 * m1 + 1e-5f);
                #pragma unroll
                for (int ni = 0; ni < 4; ++ni) {
                    int col = wave * 64 + ni * 16 + l15;
                    xS[csw(rl, col)] = f2bf((acc[mi][ni][rr] - m1) * r1 * gv[ni] + bbv[ni]);
                }
            }
        __syncthreads();
    };

    // ---- phase 2: update (MODE1, keep==true also refreshes xS) or copy -----
    auto phase2 = [&](const unsigned short* a_in, const unsigned short* t_in,
                      const unsigned short* lat_in, const float* g,
                      const float* b, const float* logit,
                      unsigned short* outp, bool keep) {
        if constexpr (MODE == 0) {
            #pragma unroll
            for (int rr = 0; rr < 4; ++rr) {
                const int rl = wave * 4 + rr;
                const size_t gbase = (size_t)(bm + rl) * DCC + c0;
                short8 cm = *(const short8*)&xS[csw(rl, c0)];
                *(short8*)(outp + gbase) = cm;
            }
            // xS already holds new acts (comp == acts for bottom-up)
        } else {
            float gr[8], br[8], pr[8];
            {
                float4 ga = *(const float4*)(g + c0),     gb = *(const float4*)(g + c0 + 4);
                float4 ba = *(const float4*)(b + c0),     bb2 = *(const float4*)(b + c0 + 4);
                float4 pA = *(const float4*)(logit + c0), pB = *(const float4*)(logit + c0 + 4);
                float gt[8] = {ga.x,ga.y,ga.z,ga.w,gb.x,gb.y,gb.z,gb.w};
                float bt[8] = {ba.x,ba.y,ba.z,ba.w,bb2.x,bb2.y,bb2.z,bb2.w};
                float pt[8] = {pA.x,pA.y,pA.z,pA.w,pB.x,pB.y,pB.z,pB.w};
                #pragma unroll
                for (int j = 0; j < 8; ++j) {
                    gr[j] = gt[j]; br[j] = bt[j];
                    pr[j] = 1.0f / (1.0f + __expf(-pt[j]));
                }
            }
            #pragma unroll
            for (int rr = 0; rr < 4; ++rr) {
                const int rl = wave * 4 + rr;
                const size_t gbase = (size_t)(bm + rl) * DCC + c0;
                short8 cm = *(const short8*)&xS[csw(rl, c0)];
                short8 ar = *(const short8*)(a_in + gbase);
                short8 tr = *(const short8*)(t_in + gbase);
                short8 lr = *(const short8*)(lat_in + gbase);
                float tv[8], s = 0.f, q = 0.f;
                #pragma unroll
                for (int j = 0; j < 8; ++j) {
                    float val = bf2f((unsigned short)ar[j])
                              + 0.5f * (bf2f((unsigned short)cm[j]) - bf2f((unsigned short)tr[j])) * pr[j]
                              + 0.1f * bf2f((unsigned short)lr[j]);
                    tv[j] = val; s += val; q += val * val;
                }
                #pragma unroll
                for (int off = 1; off < 64; off <<= 1) {
                    s += __shfl_xor(s, off, 64);
                    q += __shfl_xor(q, off, 64);
                }
                float m2 = s * (1.0f / DCC);
                float r2 = rsqrtf(q * (1.0f / DCC) - m2 * m2 + 1e-5f);
                short8 o;
                #pragma unroll
                for (int j = 0; j < 8; ++j)
                    o[j] = (short)f2bf((tv[j] - m2) * r2 * gr[j] + br[j]);
                *(short8*)(outp + gbase) = o;
                if (keep) *(short8*)&xS[csw(rl, c0)] = o;   // own location, no race
            }
        }
    };

    // ================= layer A: up-GEMM from global ==========================
    #pragma unroll
    for (int mi = 0; mi < 2; ++mi)
        #pragma unroll
        for (int ni = 0; ni < 4; ++ni)
            acc[mi][ni] = f32x4{0.f, 0.f, 0.f, 0.f};

    auto issueA = [&](int buf, int k0) {
        if (wave < 2)
            async16(Ap + (size_t)(bm + wave * 16 + lrow) * DCC + k0 + lc8,
                    &As3[buf][wave * 512]);
        #pragma unroll
        for (int r = 0; r < 4; ++r)
            async16(W0 + (size_t)((r * 8 + wave) * 16 + lrow) * DCC + k0 + lc8,
                    &Bs[buf][(r * 8 + wave) * 512]);
    };

    issueA(0, 0);
    issueA(1, 32);

    #pragma unroll
    for (int t = 0; t < 16; ++t) {
        const int cur = t % 3;
        if (t < 15) { if (wave < 2) VMCNT(5); else VMCNT(4); }
        else        { VMCNT(0); }
        __builtin_amdgcn_s_barrier();
        if (t + 2 < 16) issueA((t + 2) % 3, (t + 2) * 32);

        short8 af[2], bfr[4];
        #pragma unroll
        for (int mi = 0; mi < 2; ++mi)
            af[mi] = *(const short8*)&As3[cur][(mi * 16 + l15) * 32 + lh * 8];
        #pragma unroll
        for (int ni = 0; ni < 4; ++ni)
            bfr[ni] = *(const short8*)&Bs[cur][(wave * 64 + ni * 16 + l15) * 32 + lh * 8];
        __builtin_amdgcn_s_setprio(1);
        #pragma unroll
        for (int mi = 0; mi < 2; ++mi)
            #pragma unroll
            for (int ni = 0; ni < 4; ++ni)
                acc[mi][ni] = __builtin_amdgcn_mfma_f32_16x16x32_bf16(
                    af[mi], bfr[ni], acc[mi][ni], 0, 0, 0);
        __builtin_amdgcn_s_setprio(0);
    }

    ln1_to_xS(bias0, g0, b0);
    phase2(a0, t0, lat0, g0, b0, logit0, out0, true);
    __syncthreads();   // xS final before layer-B K-loop reads

    // ================= layer B: up-GEMM with A from xS =======================
    #pragma unroll
    for (int mi = 0; mi < 2; ++mi)
        #pragma unroll
        for (int ni = 0; ni < 4; ++ni)
            acc[mi][ni] = f32x4{0.f, 0.f, 0.f, 0.f};

    auto issueB = [&](int buf, int k0) {
        #pragma unroll
        for (int r = 0; r < 4; ++r)
            async16(W1 + (size_t)((r * 8 + wave) * 16 + lrow) * DCC + k0 + lc8,
                    &Bs[buf][(r * 8 + wave) * 512]);
    };

    issueB(0, 0);
    issueB(1, 32);

    #pragma unroll
    for (int t = 0; t < 16; ++t) {
        const int cur = t % 3;
        if (t < 15) VMCNT(4);
        else        VMCNT(0);
        __builtin_amdgcn_s_barrier();
        if (t + 2 < 16) issueB((t + 2) % 3, (t + 2) * 32);

        short8 af[2], bfr[4];
        #pragma unroll
        for (int mi = 0; mi < 2; ++mi)
            af[mi] = *(const short8*)&xS[csw(mi * 16 + l15, t * 32 + lh * 8)];
        #pragma unroll
        for (int ni = 0; ni < 4; ++ni)
            bfr[ni] = *(const short8*)&Bs[cur][(wave * 64 + ni * 16 + l15) * 32 + lh * 8];
        __builtin_amdgcn_s_setprio(1);
        #pragma unroll
        for (int mi = 0; mi < 2; ++mi)
            #pragma unroll
            for (int ni = 0; ni < 4; ++ni)
                acc[mi][ni] = __builtin_amdgcn_mfma_f32_16x16x32_bf16(
                    af[mi], bfr[ni], acc[mi][ni], 0, 0, 0);
        __builtin_amdgcn_s_setprio(0);
    }
    // all waves' xS reads complete before ln1_to_xS's red-sync allows rewrites

    ln1_to_xS(bias1, g1, b1);
    phase2(a1, t1, lat1, g1, b1, logit1, out1, false);
}

// ---------------------------------------------------------------------------
extern "C" void kernel_launch(void* const* d_in, const int* in_sizes, int n_in,
                              void* d_out, int out_size, void* d_ws, size_t ws_size,
                              hipStream_t stream)
{
    const float* qwen   = (const float*)d_in[0];
    const float* obs    = (const float*)d_in[1];
    const float* proj_W = (const float*)d_in[2];
    const float* proj_b = (const float*)d_in[3];
    const float* fuse_W = (const float*)d_in[4];
    const float* fuse_b = (const float*)d_in[5];
    const float* up_W   = (const float*)d_in[6];
    const float* up_b   = (const float*)d_in[7];
    const float* lat_W  = (const float*)d_in[8];
    const float* lat_b  = (const float*)d_in[9];
    const float* plogit = (const float*)d_in[10];
    const float* ln_g   = (const float*)d_in[11];
    const float* ln_b   = (const float*)d_in[12];
    const float* down_W = (const float*)d_in[13];
    const float* down_b = (const float*)d_in[14];
    const float* out1_W = (const float*)d_in[15];
    const float* out1_b = (const float*)d_in[16];
    const float* out2_W = (const float*)d_in[17];
    const float* out2_b = (const float*)d_in[18];
    float* out = (float*)d_out;

    // ---- ws layout (ushort); footprint 228.6 MB (proven)
    unsigned short* wsu = (unsigned short*)d_ws;
    float*          bp     = (float*)wsu;                  // 512 f32
    unsigned short* h16    = wsu + 2048;                   // head scratch
    unsigned short* M16    = wsu + 8388608;                // (4,512,2048)
    unsigned short* x0b    = wsu + 16777216;
    unsigned short* acts16[4] = {
        wsu + 20971520, wsu + 20971520 + TOKH,
        wsu + 20971520 + 2 * TOKH, wsu + 20971520 + 3 * TOKH };
    unsigned short* w16    = wsu + 37748736;
    unsigned short* fuseW16 = w16;
    unsigned short* upW16   = w16 + 1048576;
    unsigned short* latW16  = w16 + 2097152;
    unsigned short* downW16 = w16 + 3145728;
    unsigned short* out1W16 = w16 + 3932160;
    unsigned short* out2W16 = w16 + 4194304;
    unsigned short* projT16 = wsu + 47185920;              // (4,2048,512)
    unsigned short* obs16   = wsu + 47185920;              // overlays projT16

    // d_out overlays: part32 (front); pred a/b + lat0..3 (settle)
    float*          part32  = (float*)d_out;
    unsigned short* outu = (unsigned short*)d_out;
    unsigned short* pred16a = outu;
    unsigned short* pred16b = outu + TOKH;
    unsigned short* lat16[4] = { outu + 2*TOKH, outu + 3*TOKH, outu + 4*TOKH, outu + 5*TOKH };

    dim3 blk(256);
    dim3 blk512(512);

    // ---- prep: weight cvt + proj transpose + b' in one launch
    {
        PrepArgs pa;
        pa.wsrc[0] = fuse_W; pa.wsrc[1] = up_W;   pa.wsrc[2] = lat_W;
        pa.wsrc[3] = down_W; pa.wsrc[4] = out1_W; pa.wsrc[5] = out2_W;
        pa.proj_W = proj_W; pa.fuse_W = fuse_W; pa.fuse_b = fuse_b;
        pa.proj_b = proj_b;
        pa.wdst = w16; pa.projT = projT16; pa.bp = bp;
        prep_kernel<<<dim3(6208), blk, 0, stream>>>(pa);
    }

    // ---- M_o = fuseW_o @ projW_o  (512x2048 each, K=512); consumes projT16
    {
        GArgs a{};
        for (int o = 0; o < 4; ++o) {
            a.A[o] = fuseW16 + o * DCC;
            a.W[o] = projT16 + (size_t)o * DMD * DCC;
            a.bias[o] = nullptr;
            a.C[o] = M16 + (size_t)o * DCC * DMD;
        }
        gemm16<false, false><<<dim3(DMD/128, DCC/128, 4), blk, 0, stream>>>(
            a, 4 * DCC, DCC, 0, DMD, DCC);
    }

    // ---- obs -> bf16 (one BW-bound pass; overwrites dead projT16 region)
    cvt_kernel<<<dim3(4096), blk, 0, stream>>>(obs, obs16, 16777216);

    // ---- x0 split-K partials: pure-bf16 gemm16, grid 1024 = ~3-4 blocks/CU
    {
        GArgs a{};
        for (int o = 0; o < 4; ++o) {
            a.A[o] = obs16 + (size_t)o * NTOK * DMD;
            a.W[o] = M16 + (size_t)o * DCC * DMD;
            a.bias[o] = nullptr;
            a.add[o]  = nullptr;
            a.C[o] = part32 + (size_t)o * TOKH;
        }
        gemm16<true, false><<<dim3(DCC/128, NTOK/128, 4), blk, 0, stream>>>(
            a, DMD, DMD, 0, DCC, DMD);
    }
    // ---- x0 = bf16(sum partials + b')
    x0red<<<dim3(TOKH/4/256), blk, 0, stream>>>(part32, bp, x0b);

    dim3 fgrid(NTOK / 32);   // 256 blocks = 1 block/CU

    // ---- initial bottom-up pass: two paired launches
    gemm_fused2<0><<<fgrid, blk512, 0, stream>>>(
        x0b,
        upW16,                 up_b,           ln_g,           ln_b,
        nullptr, nullptr, nullptr, nullptr, acts16[0],
        upW16 + 262144,        up_b + DCC,     ln_g + DCC,     ln_b + DCC,
        nullptr, nullptr, nullptr, nullptr, acts16[1]);
    gemm_fused2<0><<<fgrid, blk512, 0, stream>>>(
        acts16[1],
        upW16 + 2 * 262144,    up_b + 2 * DCC, ln_g + 2 * DCC, ln_b + 2 * DCC,
        nullptr, nullptr, nullptr, nullptr, acts16[2],
        upW16 + 3 * 262144,    up_b + 3 * DCC, ln_g + 3 * DCC, ln_b + 3 * DCC,
        nullptr, nullptr, nullptr, nullptr, acts16[3]);

    // ---- settling iterations: z6 pred/lat batch + 2 paired fused launches
    for (int s = 0; s < 5; ++s) {
        {
            GArgs a{};
            a.A[0] = acts16[1]; a.W[0] = downW16 + (size_t)1 * DCC * DCC;
            a.bias[0] = down_b + 1 * DCC; a.C[0] = pred16a;
            a.A[1] = acts16[2]; a.W[1] = downW16 + (size_t)2 * DCC * DCC;
            a.bias[1] = down_b + 2 * DCC; a.C[1] = pred16b;
            for (int i = 0; i < 4; ++i) {
                a.A[2 + i] = acts16[i];
                a.W[2 + i] = latW16 + (size_t)i * DCC * DCC;
                a.bias[2 + i] = lat_b + i * DCC;
                a.C[2 + i] = lat16[i];
            }
            gemm16<false, false><<<dim3(DCC/128, NTOK/128, 6), blk, 0, stream>>>(
                a, DCC, DCC, 0, DCC, DCC);
        }
        // pair (L0, L1): L1's A = new acts0 (kept in xS)
        gemm_fused2<1><<<fgrid, blk512, 0, stream>>>(
            x0b,
            upW16,              up_b,           ln_g,           ln_b,
            acts16[0], pred16a, lat16[0], plogit,         acts16[0],
            upW16 + 262144,     up_b + DCC,     ln_g + DCC,     ln_b + DCC,
            acts16[1], pred16b, lat16[1], plogit + DCC,   acts16[1]);
        // pair (L2, L3): self-target layers
        gemm_fused2<1><<<fgrid, blk512, 0, stream>>>(
            acts16[1],
            upW16 + 2 * 262144, up_b + 2 * DCC, ln_g + 2 * DCC, ln_b + 2 * DCC,
            acts16[2], acts16[2], lat16[2], plogit + 2 * DCC, acts16[2],
            upW16 + 3 * 262144, up_b + 3 * DCC, ln_g + 3 * DCC, ln_b + 3 * DCC,
            acts16[3], acts16[3], lat16[3], plogit + 3 * DCC, acts16[3]);
    }

    // ---- head
    {
        GArgs a{};
        a.A[0] = acts16[3]; a.W[0] = out1W16; a.bias[0] = out1_b; a.C[0] = h16;
        gemm16<false, true><<<dim3(DCC/128, NTOK/128, 1), blk, 0, stream>>>(
            a, DCC, DCC, 0, DCC, DCC);
    }
    {
        GArgs a{};
        a.A[0] = h16; a.W[0] = out2W16; a.bias[0] = out2_b;
        a.add[0] = qwen; a.C[0] = out;
        gemm16<true, false><<<dim3(DMD/128, NTOK/128, 1), blk, 0, stream>>>(
            a, DCC, DCC, DMD, DMD, DCC);
    }
}